// Round 6
// baseline (516.577 us; speedup 1.0000x reference)
//
#include <hip/hip_runtime.h>
#include <math.h>

#define NHEAD 12
#define DH 64
#define S_LEN 4096
#define B_SZ 2
#define D_MODEL 768
#define FF_DIM 3072
#define WINSZ 128
#define NGLB 32
#define NEGV -1e9f
#define NQC 6291456L

typedef __attribute__((ext_vector_type(8))) short bf16x8;
typedef __attribute__((ext_vector_type(4))) float floatx4;

__device__ __forceinline__ unsigned short f2bf(float x) {
    union { float f; unsigned u; } v; v.f = x;
    unsigned r = v.u + 0x7fffu + ((v.u >> 16) & 1u);
    return (unsigned short)(r >> 16);
}
__device__ __forceinline__ float bf2f(unsigned short x) {
    union { unsigned u; float f; } v; v.u = ((unsigned)x) << 16;
    return v.f;
}

__device__ __forceinline__ void async_copy16(const unsigned short* g, unsigned short* l) {
    __builtin_amdgcn_global_load_lds(
        (const __attribute__((address_space(1))) void*)g,
        (__attribute__((address_space(3))) void*)l, 16, 0, 0);
}

// ---------------------------------------------------------------------------
// Fused prep: 6 weight transposes (fp32 KxN -> bf16 NxK, Wq scaled 0.125)
// + bias concat (bq scaled 0.125) + hidden fp32->bf16 conversion.
// Block ranges: [0,6912) transposes, [6912,6921) bcat, [6921,13065) conv.
// ---------------------------------------------------------------------------
__global__ __launch_bounds__(256) void prep_k(
    const float* __restrict__ Wq, const float* __restrict__ Wk,
    const float* __restrict__ Wv, const float* __restrict__ Wo,
    const float* __restrict__ Wi, const float* __restrict__ Wo2,
    unsigned short* __restrict__ wqt, unsigned short* __restrict__ wkt,
    unsigned short* __restrict__ wvt, unsigned short* __restrict__ wot,
    unsigned short* __restrict__ wit, unsigned short* __restrict__ wo2t,
    const float* __restrict__ bq, const float* __restrict__ bk,
    const float* __restrict__ bv, float* __restrict__ bcat,
    const float* __restrict__ hid, unsigned short* __restrict__ hidb)
{
    __shared__ float tile[32][33];
    const int bid = blockIdx.x;
    const int tx = threadIdx.x, ty = threadIdx.y;

    if (bid < 6912) {
        const float* src; unsigned short* dst; int K, N, nx, local; float scale = 1.f;
        if (bid < 576)       { src = Wq;  dst = wqt;  K = 768;  N = 768;  nx = 24; local = bid;        scale = 0.125f; }
        else if (bid < 1152) { src = Wk;  dst = wkt;  K = 768;  N = 768;  nx = 24; local = bid - 576;  }
        else if (bid < 1728) { src = Wv;  dst = wvt;  K = 768;  N = 768;  nx = 24; local = bid - 1152; }
        else if (bid < 2304) { src = Wo;  dst = wot;  K = 768;  N = 768;  nx = 24; local = bid - 1728; }
        else if (bid < 4608) { src = Wi;  dst = wit;  K = 768;  N = 3072; nx = 96; local = bid - 2304; }
        else                 { src = Wo2; dst = wo2t; K = 3072; N = 768;  nx = 24; local = bid - 4608; }
        const int n0 = (local % nx) * 32, k0 = (local / nx) * 32;
#pragma unroll
        for (int i = 0; i < 4; ++i)
            tile[ty + 8 * i][tx] = src[(long)(k0 + ty + 8 * i) * N + n0 + tx];
        __syncthreads();
#pragma unroll
        for (int i = 0; i < 4; ++i)
            dst[(long)(n0 + ty + 8 * i) * K + k0 + tx] = f2bf(tile[tx][ty + 8 * i] * scale);
    } else if (bid < 6921) {
        const int t = ty * 32 + tx;
        const int i = (bid - 6912) * 256 + t;
        if (i < 768) bcat[i] = bq[i] * 0.125f;
        else if (i < 1536) bcat[i] = bk[i - 768];
        else if (i < 2304) bcat[i] = bv[i - 1536];
    } else {
        const int t = ty * 32 + tx;
        const long i = ((long)(bid - 6921) * 256 + t) * 4;
        float4 v = *(const float4*)(hid + i);
        ushort4 o;
        o.x = f2bf(v.x); o.y = f2bf(v.y); o.z = f2bf(v.z); o.w = f2bf(v.w);
        *(ushort4*)(hidb + i) = o;
    }
}

// ---------------------------------------------------------------------------
// V (B,NH,S,DH) bf16 -> Vt (B,NH,DH,S) bf16
// ---------------------------------------------------------------------------
__global__ __launch_bounds__(256) void vt_k(
    const unsigned short* __restrict__ v, unsigned short* __restrict__ vt)
{
    const int bh = blockIdx.y;
    const int s0 = blockIdx.x * 32;
    const int w = threadIdx.x >> 6, lane = threadIdx.x & 63;
    const unsigned short* src = v + ((long)bh * S_LEN + s0 + w * 8) * DH + lane;
    unsigned short r[8];
#pragma unroll
    for (int j = 0; j < 8; ++j) r[j] = src[j * DH];
    unsigned short* dst = vt + ((long)bh * DH + lane) * S_LEN + s0 + w * 8;
    ushort4 lo, hi;
    lo.x = r[0]; lo.y = r[1]; lo.z = r[2]; lo.w = r[3];
    hi.x = r[4]; hi.y = r[5]; hi.z = r[6]; hi.w = r[7];
    *(ushort4*)dst = lo;
    *(ushort4*)(dst + 4) = hi;
}

// ---------------------------------------------------------------------------
// bf16 MFMA GEMM v6: A LDS-staged (3-buffer, counted vmcnt, depth 2);
// B fragments loaded DIRECTLY global->VGPR (no LDS, no ds_read, no bank
// conflict for B) — round-5 diagnosis: LDS unit saturated (~87 B/cyc =
// ceiling); B is cache-resident so its LDS round-trip is pure LDS-BW waste.
// B double-buffered in registers via 6-body macro (parity ping-pong x 3 LDS
// bufs, no register copies). Per body: issue 2 A-glds (t+2) + 4 B-loads
// (t+1) -> ds_read A frags (t) -> 16 MFMA -> vmcnt(6) + s_barrier.
// vmcnt(6) = this body's 6 issues still in flight; A(t+1)/B(t) drained.
// Requires NT % 6 == 0 (holds: 24/24/12/48). LDS = 3 x 8 KiB.
// EPI 1: gelu -> bf16.  EPI 2: fused QKV scatter (Q scale pre-folded).
// ---------------------------------------------------------------------------
#define GB(U, BC, BN, PFA, PFB, WN)                                          \
    {                                                                        \
        if (PFA) {                                                           \
            async_copy16(aSrc0 + (U + 2) * 32, &As[(U + 2) % 3][g0]);        \
            async_copy16(aSrc1 + (U + 2) * 32, &As[(U + 2) % 3][g1]);        \
        }                                                                    \
        if (PFB) {                                                           \
            BN[0] = *(const bf16x8*)(bP0 + (U + 1) * 32);                    \
            BN[1] = *(const bf16x8*)(bP1 + (U + 1) * 32);                    \
            BN[2] = *(const bf16x8*)(bP2 + (U + 1) * 32);                    \
            BN[3] = *(const bf16x8*)(bP3 + (U + 1) * 32);                    \
        }                                                                    \
        __builtin_amdgcn_sched_barrier(0);                                   \
        bf16x8 af[4];                                                        \
        _Pragma("unroll")                                                    \
        for (int i = 0; i < 4; ++i)                                          \
            af[i] = *(const bf16x8*)&As[(U) % 3][rdA + i * 512];             \
        __builtin_amdgcn_s_setprio(1);                                       \
        _Pragma("unroll")                                                    \
        for (int i = 0; i < 4; ++i)                                          \
            _Pragma("unroll")                                                \
            for (int j = 0; j < 4; ++j)                                      \
                acc[i][j] = __builtin_amdgcn_mfma_f32_16x16x32_bf16(         \
                    af[i], BC[j], acc[i][j], 0, 0, 0);                       \
        __builtin_amdgcn_s_setprio(0);                                       \
        __builtin_amdgcn_sched_barrier(0);                                   \
        if (WN == 6) {                                                       \
            asm volatile("s_waitcnt vmcnt(6)" ::: "memory");                 \
            __builtin_amdgcn_s_barrier();                                    \
        } else if (WN == 4) {                                                \
            asm volatile("s_waitcnt vmcnt(4)" ::: "memory");                 \
            __builtin_amdgcn_s_barrier();                                    \
        }                                                                    \
        __builtin_amdgcn_sched_barrier(0);                                   \
    }

template <int EPI>
__global__ __launch_bounds__(256) void gemm_bf(
    const unsigned short* __restrict__ A, const unsigned short* __restrict__ BT,
    const float* __restrict__ bias, void* __restrict__ out,
    int M, int N, int K, int nx)
{
    __shared__ unsigned short As[3][128 * 32];
    const int tid = threadIdx.x;
    const int wave = tid >> 6, lane = tid & 63;
    const int t8 = (blockIdx.x & 7) * (gridDim.x >> 3) + (blockIdx.x >> 3);
    const int m0 = (t8 / nx) * 128, n0 = (t8 % nx) * 128;
    const int wr = (wave >> 1) * 64, wc = (wave & 1) * 64;

    floatx4 acc[4][4];
#pragma unroll
    for (int i = 0; i < 4; ++i)
#pragma unroll
        for (int j = 0; j < 4; ++j) acc[i][j] = (floatx4){0.f, 0.f, 0.f, 0.f};

    const int srow = lane >> 2;
    const int schk = (((lane & 3) ^ (srow & 3))) * 8;   // XOR-swizzled A stage
    const int r = lane & 15, ln4 = lane >> 4;
    const int q8 = (ln4 ^ (lane & 3)) * 8;              // XOR-swizzled A read
    const int rdA = (wr + r) * 32 + q8;

    const int NT = K >> 5;                              // NT % 6 == 0
    const unsigned short* aSrc0 = A + (long)(m0 + wave * 32 + srow) * K + schk;
    const unsigned short* aSrc1 = A + (long)(m0 + wave * 32 + 16 + srow) * K + schk;
    // direct B fragment pointers: lane r=row, ln4*8 = true k offset
    const unsigned short* bP0 = BT + (long)(n0 + wc +  0 + r) * K + ln4 * 8;
    const unsigned short* bP1 = BT + (long)(n0 + wc + 16 + r) * K + ln4 * 8;
    const unsigned short* bP2 = BT + (long)(n0 + wc + 32 + r) * K + ln4 * 8;
    const unsigned short* bP3 = BT + (long)(n0 + wc + 48 + r) * K + ln4 * 8;
    const int g0 = wave * 1024, g1 = wave * 1024 + 512;

    bf16x8 b0[4], b1[4];

    // prologue: A(0)->buf0, A(1)->buf1, B(0)->b0
    async_copy16(aSrc0, &As[0][g0]);
    async_copy16(aSrc1, &As[0][g1]);
    async_copy16(aSrc0 + 32, &As[1][g0]);
    async_copy16(aSrc1 + 32, &As[1][g1]);
    b0[0] = *(const bf16x8*)bP0;
    b0[1] = *(const bf16x8*)bP1;
    b0[2] = *(const bf16x8*)bP2;
    b0[3] = *(const bf16x8*)bP3;
    asm volatile("s_waitcnt vmcnt(6)" ::: "memory");
    __builtin_amdgcn_s_barrier();
    __builtin_amdgcn_sched_barrier(0);

    for (int t6 = 0; t6 < NT - 6; t6 += 6) {
        GB(0, b0, b1, 1, 1, 6)
        GB(1, b1, b0, 1, 1, 6)
        GB(2, b0, b1, 1, 1, 6)
        GB(3, b1, b0, 1, 1, 6)
        GB(4, b0, b1, 1, 1, 6)
        GB(5, b1, b0, 1, 1, 6)
        aSrc0 += 192; aSrc1 += 192;
        bP0 += 192; bP1 += 192; bP2 += 192; bP3 += 192;
    }
    // tail macro (t = NT-6 .. NT-1)
    GB(0, b0, b1, 1, 1, 6)
    GB(1, b1, b0, 1, 1, 6)
    GB(2, b0, b1, 1, 1, 6)
    GB(3, b1, b0, 1, 1, 6)
    GB(4, b0, b1, 0, 1, 4)
    GB(5, b1, b0, 0, 0, 0)

    const int col_l = lane & 15, row_l = (lane >> 4) * 4;
#pragma unroll
    for (int i = 0; i < 4; ++i) {
#pragma unroll
        for (int j = 0; j < 4; ++j) {
            const int n = n0 + wc + j * 16 + col_l;
            const float bv = bias[n];
#pragma unroll
            for (int rg = 0; rg < 4; ++rg) {
                const int m = m0 + wr + i * 16 + row_l + rg;
                float v = acc[i][j][rg] + bv;
                if (EPI == 1) {
                    v = 0.5f * v * (1.f + erff(v * 0.70710678118654752f));
                    ((unsigned short*)out)[(long)m * N + n] = f2bf(v);
                } else {
                    const int bb = m >> 12, s = m & 4095;
                    const int part = n / 768;          // 0=q, 1=k, 2=v
                    const int nn = n - part * 768;
                    const int hh = nn >> 6, dh = nn & 63;
                    ((unsigned short*)out)[(long)part * NQC +
                        (((long)bb * NHEAD + hh) * S_LEN + s) * DH + dh] = f2bf(v);
                }
            }
        }
    }
}

// ---------------------------------------------------------------------------
// Split-K (x2) bf16 MFMA GEMM, same A-LDS / B-direct pipeline. Raw fp32
// partials; reduction happens inside ln2p_k.
// ---------------------------------------------------------------------------
__global__ __launch_bounds__(256) void gemm_sp(
    const unsigned short* __restrict__ A, const unsigned short* __restrict__ BT,
    float* __restrict__ p0, float* __restrict__ p1,
    int M, int N, int K2, int nx, int ntile)
{
    __shared__ unsigned short As[3][128 * 32];
    const int tid = threadIdx.x;
    const int wave = tid >> 6, lane = tid & 63;
    const int t8 = (blockIdx.x & 7) * (gridDim.x >> 3) + (blockIdx.x >> 3);
    const int slice = t8 >= ntile;
    const int tile = t8 - slice * ntile;
    const int m0 = (tile / nx) * 128, n0 = (tile % nx) * 128;
    const int kbeg = slice * K2;
    float* P = slice ? p1 : p0;
    const int wr = (wave >> 1) * 64, wc = (wave & 1) * 64;

    floatx4 acc[4][4];
#pragma unroll
    for (int i = 0; i < 4; ++i)
#pragma unroll
        for (int j = 0; j < 4; ++j) acc[i][j] = (floatx4){0.f, 0.f, 0.f, 0.f};

    const int srow = lane >> 2;
    const int schk = (((lane & 3) ^ (srow & 3))) * 8;
    const int r = lane & 15, ln4 = lane >> 4;
    const int q8 = (ln4 ^ (lane & 3)) * 8;
    const int rdA = (wr + r) * 32 + q8;
    const long Kl = (long)K2 * 2;

    const int NT = K2 >> 5;                             // NT % 6 == 0
    const unsigned short* aSrc0 = A + (long)(m0 + wave * 32 + srow) * Kl + kbeg + schk;
    const unsigned short* aSrc1 = A + (long)(m0 + wave * 32 + 16 + srow) * Kl + kbeg + schk;
    const unsigned short* bP0 = BT + (long)(n0 + wc +  0 + r) * Kl + kbeg + ln4 * 8;
    const unsigned short* bP1 = BT + (long)(n0 + wc + 16 + r) * Kl + kbeg + ln4 * 8;
    const unsigned short* bP2 = BT + (long)(n0 + wc + 32 + r) * Kl + kbeg + ln4 * 8;
    const unsigned short* bP3 = BT + (long)(n0 + wc + 48 + r) * Kl + kbeg + ln4 * 8;
    const int g0 = wave * 1024, g1 = wave * 1024 + 512;

    bf16x8 b0[4], b1[4];

    async_copy16(aSrc0, &As[0][g0]);
    async_copy16(aSrc1, &As[0][g1]);
    async_copy16(aSrc0 + 32, &As[1][g0]);
    async_copy16(aSrc1 + 32, &As[1][g1]);
    b0[0] = *(const bf16x8*)bP0;
    b0[1] = *(const bf16x8*)bP1;
    b0[2] = *(const bf16x8*)bP2;
    b0[3] = *(const bf16x8*)bP3;
    asm volatile("s_waitcnt vmcnt(6)" ::: "memory");
    __builtin_amdgcn_s_barrier();
    __builtin_amdgcn_sched_barrier(0);

    for (int t6 = 0; t6 < NT - 6; t6 += 6) {
        GB(0, b0, b1, 1, 1, 6)
        GB(1, b1, b0, 1, 1, 6)
        GB(2, b0, b1, 1, 1, 6)
        GB(3, b1, b0, 1, 1, 6)
        GB(4, b0, b1, 1, 1, 6)
        GB(5, b1, b0, 1, 1, 6)
        aSrc0 += 192; aSrc1 += 192;
        bP0 += 192; bP1 += 192; bP2 += 192; bP3 += 192;
    }
    GB(0, b0, b1, 1, 1, 6)
    GB(1, b1, b0, 1, 1, 6)
    GB(2, b0, b1, 1, 1, 6)
    GB(3, b1, b0, 1, 1, 6)
    GB(4, b0, b1, 0, 1, 4)
    GB(5, b1, b0, 0, 0, 0)

    const int col_l = lane & 15, row_l = (lane >> 4) * 4;
#pragma unroll
    for (int i = 0; i < 4; ++i)
#pragma unroll
        for (int j = 0; j < 4; ++j) {
            const int n = n0 + wc + j * 16 + col_l;
#pragma unroll
            for (int rg = 0; rg < 4; ++rg) {
                const int m = m0 + wr + i * 16 + row_l + rg;
                P[(long)m * N + n] = acc[i][j][rg];
            }
        }
}

// ---------------------------------------------------------------------------
// Fused attention: blocks [0,24) = global-query path (4 waves, 16 iters),
// blocks [24,792) = band path (b,h,chunk; 4 waves x 32 queries).
// Glob blocks launch FIRST so they overlap the band wave-front.
// Band suppresses stores for q0 < NGLB (those rows belong to glob) -> no race.
// ---------------------------------------------------------------------------
__global__ __launch_bounds__(256) void attn_k(
    const unsigned short* __restrict__ q, const unsigned short* __restrict__ k,
    const unsigned short* __restrict__ vt, const float* __restrict__ am,
    unsigned short* __restrict__ ctx)
{
    __shared__ __align__(16) unsigned char smem[28800];
    const int blk = blockIdx.x;
    const int tid = threadIdx.x;
    const int wave = tid >> 6, lane = tid & 63;
    const int ln15 = lane & 15, ln4 = lane >> 4;

    if (blk >= 24) {
        // ---------------- band path ----------------
        unsigned short* Ks = (unsigned short*)smem;            // 32*72
        unsigned short* Vs = Ks + 32 * 72;                     // 64*40
        unsigned short* Ps = Vs + 64 * 40;                     // [4][32*40]

        const int bb = blk - 24;
        const int c = bb & 31;
        const int h = (bb >> 5) % NHEAD;
        const int b = bb / (32 * NHEAD);
        const long bh = (long)b * NHEAD + h;

        const unsigned short* kh  = k + bh * S_LEN * DH;
        const unsigned short* vth = vt + bh * (long)DH * S_LEN;
        const float* amb = am + (long)b * S_LEN;

        const int q0 = c * WINSZ + wave * 32;

        bf16x8 qf[2][2];
#pragma unroll
        for (int nt = 0; nt < 2; ++nt)
#pragma unroll
            for (int ks = 0; ks < 2; ++ks)
                qf[nt][ks] = *(const bf16x8*)(q + (bh * S_LEN + q0 + nt * 16 + ln15) * DH
                                              + ks * 32 + ln4 * 8);

        floatx4 o[4][2];
#pragma unroll
        for (int mt = 0; mt < 4; ++mt)
#pragma unroll
            for (int nt = 0; nt < 2; ++nt) o[mt][nt] = (floatx4){0.f, 0.f, 0.f, 0.f};
        float m_r[2] = {-1e30f, -1e30f}, l_r[2] = {0.f, 0.f};

        const int sk_key = tid >> 3, sk_ch = tid & 7;
        const int sv_dim = tid & 63, sv_ch = tid >> 6;
        const bf16x8 zero8 = {0, 0, 0, 0, 0, 0, 0, 0};

        for (int tile = 0; tile < 13; ++tile) {
            const bool glob = (tile == 12);
            const int kbase = glob ? 0 : (c * WINSZ - WINSZ + tile * 32);

            __syncthreads();
            {
                int kpos = kbase + sk_key;
                bf16x8 val = zero8;
                if ((unsigned)kpos < (unsigned)S_LEN)
                    val = *(const bf16x8*)(kh + (long)kpos * DH + sk_ch * 8);
                *(bf16x8*)(&Ks[sk_key * 72 + sk_ch * 8]) = val;
            }
            {
                int kc = kbase + sv_ch * 8;
                bf16x8 val = zero8;
                if (kc >= 0 && kc + 8 <= S_LEN)
                    val = *(const bf16x8*)(vth + (long)sv_dim * S_LEN + kc);
                *(bf16x8*)(&Vs[sv_dim * 40 + sv_ch * 8]) = val;
            }
            __syncthreads();

            bf16x8 ak[2][2];
#pragma unroll
            for (int mt = 0; mt < 2; ++mt)
#pragma unroll
                for (int ks = 0; ks < 2; ++ks)
                    ak[mt][ks] = *(const bf16x8*)(&Ks[(mt * 16 + ln15) * 72 + ks * 32 + ln4 * 8]);

            floatx4 s[2][2];
#pragma unroll
            for (int mt = 0; mt < 2; ++mt)
#pragma unroll
                for (int nt = 0; nt < 2; ++nt) {
                    floatx4 acc = (floatx4){0.f, 0.f, 0.f, 0.f};
                    acc = __builtin_amdgcn_mfma_f32_16x16x32_bf16(ak[mt][0], qf[nt][0], acc, 0, 0, 0);
                    acc = __builtin_amdgcn_mfma_f32_16x16x32_bf16(ak[mt][1], qf[nt][1], acc, 0, 0, 0);
                    s[mt][nt] = acc;
                }

#pragma unroll
            for (int mt = 0; mt < 2; ++mt) {
                const int kp0 = kbase + mt * 16 + ln4 * 4;
#pragma unroll
                for (int rg = 0; rg < 4; ++rg) {
                    const int kpos = kp0 + rg;
                    const bool kin = (unsigned)kpos < (unsigned)S_LEN;
                    const float amv = kin ? amb[kpos] : 0.f;
#pragma unroll
                    for (int nt = 0; nt < 2; ++nt) {
                        const int qpos = q0 + nt * 16 + ln15;
                        const int dlt = kpos > qpos ? kpos - qpos : qpos - kpos;
                        const bool valid = glob || (kpos >= NGLB && kin && dlt <= WINSZ);
                        s[mt][nt][rg] = valid ? s[mt][nt][rg] + amv : NEGV;
                    }
                }
            }

            float alpha[2];
#pragma unroll
            for (int nt = 0; nt < 2; ++nt) {
                float mx = s[0][nt][0];
#pragma unroll
                for (int rg = 1; rg < 4; ++rg) mx = fmaxf(mx, s[0][nt][rg]);
#pragma unroll
                for (int rg = 0; rg < 4; ++rg) mx = fmaxf(mx, s[1][nt][rg]);
                mx = fmaxf(mx, __shfl_xor(mx, 16));
                mx = fmaxf(mx, __shfl_xor(mx, 32));
                const float mn = fmaxf(m_r[nt], mx);
                alpha[nt] = __expf(m_r[nt] - mn);
                m_r[nt] = mn;
            }

#pragma unroll
            for (int nt = 0; nt < 2; ++nt) {
                float sum = 0.f;
#pragma unroll
                for (int mt = 0; mt < 2; ++mt) {
                    ushort4 pk;
#pragma unroll
                    for (int rg = 0; rg < 4; ++rg) {
                        const float p = __expf(s[mt][nt][rg] - m_r[nt]);
                        sum += p;
                        ((unsigned short*)&pk)[rg] = f2bf(p);
                    }
                    *(ushort4*)(&Ps[wave * 1280 + (nt * 16 + ln15) * 40 + mt * 16 + ln4 * 4]) = pk;
                }
                sum += __shfl_xor(sum, 16);
                sum += __shfl_xor(sum, 32);
                l_r[nt] = l_r[nt] * alpha[nt] + sum;
            }

#pragma unroll
            for (int mt = 0; mt < 4; ++mt)
#pragma unroll
                for (int nt = 0; nt < 2; ++nt)
#pragma unroll
                    for (int rg = 0; rg < 4; ++rg) o[mt][nt][rg] *= alpha[nt];

            bf16x8 av[4], bp[2];
#pragma unroll
            for (int mt = 0; mt < 4; ++mt)
                av[mt] = *(const bf16x8*)(&Vs[(mt * 16 + ln15) * 40 + ln4 * 8]);
#pragma unroll
            for (int nt = 0; nt < 2; ++nt)
                bp[nt] = *(const bf16x8*)(&Ps[wave * 1280 + (nt * 16 + ln15) * 40 + ln4 * 8]);
#pragma unroll
            for (int mt = 0; mt < 4; ++mt)
#pragma unroll
                for (int nt = 0; nt < 2; ++nt)
                    o[mt][nt] = __builtin_amdgcn_mfma_f32_16x16x32_bf16(
                        av[mt], bp[nt], o[mt][nt], 0, 0, 0);
        }

        if (q0 >= NGLB) {
            const float inv0 = 1.f / l_r[0], inv1 = 1.f / l_r[1];
#pragma unroll
            for (int nt = 0; nt < 2; ++nt) {
                const float inv = nt ? inv1 : inv0;
                const long row = (long)b * S_LEN + q0 + nt * 16 + ln15;
#pragma unroll
                for (int mt = 0; mt < 4; ++mt) {
                    ushort4 ov;
#pragma unroll
                    for (int rg = 0; rg < 4; ++rg)
                        ((unsigned short*)&ov)[rg] = f2bf(o[mt][nt][rg] * inv);
                    *(ushort4*)(ctx + row * D_MODEL + h * DH + mt * 16 + ln4 * 4) = ov;
                }
            }
        }
    } else {
        // ---------------- global-query path (4 waves, 16 iters) ----------------
        unsigned short* Psg = (unsigned short*)smem;           // [4][32*72]
        float* Om   = (float*)(smem + 18432);                  // 64*36
        float* mW   = (float*)(smem + 27648);                  // [4][32]
        float* lW   = (float*)(smem + 28160);                  // [4][32]
        float* lTot = (float*)(smem + 28672);                  // [32]

        const int bh = blk;
        const int b = bh / NHEAD, h = bh % NHEAD;

        const unsigned short* kh  = k + (long)bh * S_LEN * DH;
        const unsigned short* vth = vt + (long)bh * DH * S_LEN;
        const float* amb = am + (long)b * S_LEN;

        bf16x8 qf[2][2];
#pragma unroll
        for (int nt = 0; nt < 2; ++nt)
#pragma unroll
            for (int ks = 0; ks < 2; ++ks)
                qf[nt][ks] = *(const bf16x8*)(q + ((long)bh * S_LEN + nt * 16 + ln15) * DH
                                              + ks * 32 + ln4 * 8);

        floatx4 o[4][2];
#pragma unroll
        for (int mt = 0; mt < 4; ++mt)
#pragma unroll
            for (int nt = 0; nt < 2; ++nt) o[mt][nt] = (floatx4){0.f, 0.f, 0.f, 0.f};
        float m_r[2] = {-1e30f, -1e30f}, l_r[2] = {0.f, 0.f};

        for (int it = 0; it < 16; ++it) {
            const int kbase = it * 256 + wave * 64;

            bf16x8 ak[4][2];
#pragma unroll
            for (int mt = 0; mt < 4; ++mt)
#pragma unroll
                for (int ks = 0; ks < 2; ++ks)
                    ak[mt][ks] = *(const bf16x8*)(kh + (long)(kbase + mt * 16 + ln15) * DH
                                                  + ks * 32 + ln4 * 8);

            floatx4 s[4][2];
#pragma unroll
            for (int mt = 0; mt < 4; ++mt)
#pragma unroll
                for (int nt = 0; nt < 2; ++nt) {
                    floatx4 acc = (floatx4){0.f, 0.f, 0.f, 0.f};
                    acc = __builtin_amdgcn_mfma_f32_16x16x32_bf16(ak[mt][0], qf[nt][0], acc, 0, 0, 0);
                    acc = __builtin_amdgcn_mfma_f32_16x16x32_bf16(ak[mt][1], qf[nt][1], acc, 0, 0, 0);
                    s[mt][nt] = acc;
                }

#pragma unroll
            for (int mt = 0; mt < 4; ++mt) {
                const int kp0 = kbase + mt * 16 + ln4 * 4;
#pragma unroll
                for (int rg = 0; rg < 4; ++rg) {
                    const float amv = amb[kp0 + rg];
#pragma unroll
                    for (int nt = 0; nt < 2; ++nt) s[mt][nt][rg] += amv;
                }
            }

            float alpha[2];
#pragma unroll
            for (int nt = 0; nt < 2; ++nt) {
                float mx = s[0][nt][0];
#pragma unroll
                for (int mt = 0; mt < 4; ++mt)
#pragma unroll
                    for (int rg = 0; rg < 4; ++rg) mx = fmaxf(mx, s[mt][nt][rg]);
                mx = fmaxf(mx, __shfl_xor(mx, 16));
                mx = fmaxf(mx, __shfl_xor(mx, 32));
                const float mn = fmaxf(m_r[nt], mx);
                alpha[nt] = __expf(m_r[nt] - mn);
                m_r[nt] = mn;
            }

#pragma unroll
            for (int nt = 0; nt < 2; ++nt) {
                float sum = 0.f;
#pragma unroll
                for (int mt = 0; mt < 4; ++mt) {
                    ushort4 pk;
#pragma unroll
                    for (int rg = 0; rg < 4; ++rg) {
                        const float p = __expf(s[mt][nt][rg] - m_r[nt]);
                        sum += p;
                        ((unsigned short*)&pk)[rg] = f2bf(p);
                    }
                    *(ushort4*)(&Psg[wave * 2304 + (nt * 16 + ln15) * 72 + mt * 16 + ln4 * 4]) = pk;
                }
                sum += __shfl_xor(sum, 16);
                sum += __shfl_xor(sum, 32);
                l_r[nt] = l_r[nt] * alpha[nt] + sum;
            }

#pragma unroll
            for (int mt = 0; mt < 4; ++mt)
#pragma unroll
                for (int nt = 0; nt < 2; ++nt)
#pragma unroll
                    for (int rg = 0; rg < 4; ++rg) o[mt][nt][rg] *= alpha[nt];

            bf16x8 av[4][2], bp[2][2];
#pragma unroll
            for (int mt = 0; mt < 4; ++mt)
#pragma unroll
                for (int ks = 0; ks < 2; ++ks)
                    av[mt][ks] = *(const bf16x8*)(vth + (long)(mt * 16 + ln15) * S_LEN
                                                  + kbase + ks * 32 + ln4 * 8);
#pragma unroll
            for (int nt = 0; nt < 2; ++nt)
#pragma unroll
                for (int ks = 0; ks < 2; ++ks)
                    bp[nt][ks] = *(const bf16x8*)(&Psg[wave * 2304 + (nt * 16 + ln15) * 72
                                                  + ks * 32 + ln4 * 8]);
#pragma unroll
            for (int mt = 0; mt < 4; ++mt)
#pragma unroll
                for (int nt = 0; nt < 2; ++nt) {
                    o[mt][nt] = __builtin_amdgcn_mfma_f32_16x16x32_bf16(
                        av[mt][0], bp[nt][0], o[mt][nt], 0, 0, 0);
                    o[mt][nt] = __builtin_amdgcn_mfma_f32_16x16x32_bf16(
                        av[mt][1], bp[nt][1], o[mt][nt], 0, 0, 0);
                }
        }

        if (ln4 == 0) {
#pragma unroll
            for (int nt = 0; nt < 2; ++nt) {
                mW[wave * 32 + nt * 16 + ln15] = m_r[nt];
                lW[wave * 32 + nt * 16 + ln15] = l_r[nt];
            }
        }
        for (int i = tid; i < 64 * 36; i += 256) Om[i] = 0.f;
        __syncthreads();

        float f[2];
#pragma unroll
        for (int nt = 0; nt < 2; ++nt) {
            const int qq = nt * 16 + ln15;
            float mt_ = mW[qq];
#pragma unroll
            for (int w = 1; w < 4; ++w) mt_ = fmaxf(mt_, mW[w * 32 + qq]);
            float lt = 0.f;
#pragma unroll
            for (int w = 0; w < 4; ++w) lt += __expf(mW[w * 32 + qq] - mt_) * lW[w * 32 + qq];
            f[nt] = __expf(m_r[nt] - mt_);
            if (wave == 0 && ln4 == 0) lTot[qq] = lt;
        }
#pragma unroll
        for (int mt = 0; mt < 4; ++mt)
#pragma unroll
            for (int nt = 0; nt < 2; ++nt)
#pragma unroll
                for (int rg = 0; rg < 4; ++rg) o[mt][nt][rg] *= f[nt];

        for (int wv = 0; wv < 4; ++wv) {
            if (wave == wv) {
#pragma unroll
                for (int mt = 0; mt < 4; ++mt)
#pragma unroll
                    for (int nt = 0; nt < 2; ++nt)
#pragma unroll
                        for (int rg = 0; rg < 4; ++rg)
                            Om[(mt * 16 + ln4 * 4 + rg) * 36 + nt * 16 + ln15] += o[mt][nt][rg];
            }
            __syncthreads();
        }

        const int qq = tid >> 3, d0 = (tid & 7) * 8;
        const float inv = 1.f / lTot[qq];
        ushort4 ov0, ov1;
#pragma unroll
        for (int i = 0; i < 4; ++i)
            ((unsigned short*)&ov0)[i] = f2bf(Om[(d0 + i) * 36 + qq] * inv);
#pragma unroll
        for (int i = 0; i < 4; ++i)
            ((unsigned short*)&ov1)[i] = f2bf(Om[(d0 + 4 + i) * 36 + qq] * inv);
        unsigned short* dst = ctx + ((long)b * S_LEN + qq) * D_MODEL + h * DH + d0;
        *(ushort4*)dst = ov0;
        *(ushort4*)(dst + 4) = ov1;
    }
}

// ---------------------------------------------------------------------------
// Fused split-K reduce + bias + residual + LayerNorm. x = p0+p1+bias+resid.
// One block per row (768 cols). Shfl wave-reduce (2 syncs, not 16).
// ---------------------------------------------------------------------------
__global__ __launch_bounds__(256) void ln2p_k(
    const float* __restrict__ p0, const float* __restrict__ p1,
    const float* __restrict__ bias, const float* __restrict__ resid,
    float* __restrict__ out, unsigned short* __restrict__ out_bf,
    const float* __restrict__ gw, const float* __restrict__ bw)
{
    __shared__ float red[8];
    const long base = (long)blockIdx.x * D_MODEL;
    const int t = threadIdx.x;
    const int wv = t >> 6, lane = t & 63;
    float v0 = p0[base + t]       + p1[base + t]       + bias[t]       + resid[base + t];
    float v1 = p0[base + t + 256] + p1[base + t + 256] + bias[t + 256] + resid[base + t + 256];
    float v2 = p0[base + t + 512] + p1[base + t + 512] + bias[t + 512] + resid[base + t + 512];

    float s = v0 + v1 + v2;
#pragma unroll
    for (int off = 32; off; off >>= 1) s += __shfl_xor(s, off);
    if (lane == 0) red[wv] = s;
    __syncthreads();
    const float mu = (red[0] + red[1] + red[2] + red[3]) * (1.f / 768.f);

    const float d0 = v0 - mu, d1 = v1 - mu, d2 = v2 - mu;
    float s2 = d0 * d0 + d1 * d1 + d2 * d2;
#pragma unroll
    for (int off = 32; off; off >>= 1) s2 += __shfl_xor(s2, off);
    if (lane == 0) red[4 + wv] = s2;
    __syncthreads();
    const float var = (red[4] + red[5] + red[6] + red[7]) * (1.f / 768.f);
    const float rs = rsqrtf(var + 1e-12f);

    const float y0 = d0 * rs * gw[t] + bw[t];
    const float y1 = d1 * rs * gw[t + 256] + bw[t + 256];
    const float y2 = d2 * rs * gw[t + 512] + bw[t + 512];
    if (out) {
        float* y = out + base;
        y[t] = y0; y[t + 256] = y1; y[t + 512] = y2;
    }
    if (out_bf) {
        unsigned short* yb = out_bf + base;
        yb[t] = f2bf(y0); yb[t + 256] = f2bf(y1); yb[t + 512] = f2bf(y2);
    }
}

// ---------------------------------------------------------------------------
extern "C" void kernel_launch(void* const* d_in, const int* in_sizes, int n_in,
                              void* d_out, int out_size, void* d_ws, size_t ws_size,
                              hipStream_t stream)
{
    const float* hid  = (const float*)d_in[0];
    const float* am   = (const float*)d_in[1];
    const float* Wq   = (const float*)d_in[2];
    const float* bq   = (const float*)d_in[3];
    const float* Wk   = (const float*)d_in[4];
    const float* bk   = (const float*)d_in[5];
    const float* Wv   = (const float*)d_in[6];
    const float* bv   = (const float*)d_in[7];
    const float* Wo   = (const float*)d_in[8];
    const float* bo   = (const float*)d_in[9];
    const float* ln1g = (const float*)d_in[10];
    const float* ln1b = (const float*)d_in[11];
    const float* Wi   = (const float*)d_in[12];
    const float* bi   = (const float*)d_in[13];
    const float* Wo2  = (const float*)d_in[14];
    const float* bo2  = (const float*)d_in[15];
    const float* ln2g = (const float*)d_in[16];
    const float* ln2b = (const float*)d_in[17];

    const long M  = (long)B_SZ * S_LEN;                 // 8192
    const long NQ = NQC;                                // 6291456

    unsigned short* W16 = (unsigned short*)d_ws;
    unsigned short* qb   = W16;             // bf16 (B,NH,S,DH) — q|k|v contiguous
    unsigned short* kb   = W16 + NQ;
    unsigned short* vb   = W16 + 2 * NQ;
    unsigned short* vtb  = W16 + 3 * NQ;    // bf16 (B,NH,DH,S)
    unsigned short* ctxb = W16 + 4 * NQ;    // bf16 (B,S,768)
    unsigned short* hidb = W16 + 5 * NQ;    // bf16 hidden
    unsigned short* wqt  = W16 + 6 * NQ;    // [Wq|Wk|Wv]^T contiguous 2304x768
    unsigned short* wkt  = wqt + 589824;
    unsigned short* wvt  = wkt + 589824;
    unsigned short* wot  = wvt + 589824;
    unsigned short* wit  = wot + 589824;    // 2359296
    unsigned short* wo2t = wit + 2359296;   // 2359296 -> ends at u16 44826624
    float* tmp   = (float*)(W16 + 44826624);  // attn_out fp32 -> ends u16 57409536
    float* partB1 = (float*)(W16 + 57409536); // Wo2 split slice1 -> ends u16 69992448
    float* bcat  = (float*)(W16 + 69992448);  // 2304 fp32
    // aliases over dead regions:
    float* partA0 = (float*)W16;                  // Wo slice0 (over qb,kb)
    float* partA1 = (float*)(W16 + 2 * NQ);       // Wo slice1 (over vb,vtb)
    unsigned short* interb = W16;                 // Wi out (over qb..vtb)
    unsigned short* attnb  = hidb;                // LN1 bf16 (over hidb)
    float* partB0 = (float*)(W16 + 4 * NQ);       // Wo2 slice0 (over ctxb,hidb)
    (void)ws_size; (void)in_sizes; (void)n_in; (void)out_size;

    // fused prep: 6 transposes (+0.125 fold into Wq) + bcat (+0.125 bq) + conv
    prep_k<<<dim3(13065), dim3(32, 8), 0, stream>>>(
        Wq, Wk, Wv, Wo, Wi, Wo2, wqt, wkt, wvt, wot, wit, wo2t,
        bq, bk, bv, bcat, hid, hidb);

    dim3 blk(256);

    // fused QKV: one GEMM, N = 2304, scatter to qb/kb/vb
    gemm_bf<2><<<dim3(1152), blk, 0, stream>>>(hidb, wqt, bcat, qb,
                                               M, 2304, 768, 18);

    vt_k<<<dim3(128, 24), blk, 0, stream>>>(vb, vtb);

    // fused band + global attention (glob blocks first for overlap)
    attn_k<<<dim3(792), blk, 0, stream>>>(qb, kb, vtb, am, ctxb);

    // Wo split-K x2 -> partA0/partA1 ; LN1 fuses reduce+bias+resid
    gemm_sp<<<dim3(768), blk, 0, stream>>>(ctxb, wot, partA0, partA1,
                                           M, 768, 384, 6, 384);
    ln2p_k<<<dim3(M), blk, 0, stream>>>(partA0, partA1, bo, hid,
                                        tmp, attnb, ln1g, ln1b);

    // inter = gelu(attn_out @ Wi + bi)
    gemm_bf<1><<<dim3(1536), blk, 0, stream>>>(attnb, wit, bi, interb,
                                               M, 3072, 768, 24);

    // Wo2 split-K x2 -> partB0/partB1 ; LN2 fuses reduce+bias+resid
    gemm_sp<<<dim3(768), blk, 0, stream>>>(interb, wo2t, partB0, partB1,
                                           M, 768, 1536, 6, 384);
    ln2p_k<<<dim3(M), blk, 0, stream>>>(partB0, partB1, bo2, tmp,
                                        (float*)d_out, nullptr, ln2g, ln2b);
}

// Round 7
// 419.515 us; speedup vs baseline: 1.2314x; 1.2314x over previous
//
#include <hip/hip_runtime.h>
#include <math.h>

#define NHEAD 12
#define DH 64
#define S_LEN 4096
#define B_SZ 2
#define D_MODEL 768
#define FF_DIM 3072
#define WINSZ 128
#define NGLB 32
#define NEGV -1e9f
#define NQC 6291456L

typedef __attribute__((ext_vector_type(8))) short bf16x8;
typedef __attribute__((ext_vector_type(4))) float floatx4;

__device__ __forceinline__ unsigned short f2bf(float x) {
    union { float f; unsigned u; } v; v.f = x;
    unsigned r = v.u + 0x7fffu + ((v.u >> 16) & 1u);
    return (unsigned short)(r >> 16);
}
__device__ __forceinline__ float bf2f(unsigned short x) {
    union { unsigned u; float f; } v; v.u = ((unsigned)x) << 16;
    return v.f;
}

__device__ __forceinline__ void async_copy16(const unsigned short* g, unsigned short* l) {
    __builtin_amdgcn_global_load_lds(
        (const __attribute__((address_space(1))) void*)g,
        (__attribute__((address_space(3))) void*)l, 16, 0, 0);
}

// ---------------------------------------------------------------------------
// Fused prep. Weights are written in MFMA FRAGMENT ORDER:
//   frag[nt][kt][g][lane][e] = W^T[nt*128 + g*16 + (lane&15)][kt*32 + (lane>>4)*8 + e]
// so a wave's 4 B-fragments per k-tile are 4 contiguous dwordx4 loads from
// one 4KB block (col-groups g..g+3). Buffer sizes identical to plain n x K.
// Wq/bq pre-scaled by 0.125. Block ranges: [0,6912) transposes,
// [6912,6921) bcat, [6921,13065) conv.
// ---------------------------------------------------------------------------
__global__ __launch_bounds__(256) void prep_k(
    const float* __restrict__ Wq, const float* __restrict__ Wk,
    const float* __restrict__ Wv, const float* __restrict__ Wo,
    const float* __restrict__ Wi, const float* __restrict__ Wo2,
    unsigned short* __restrict__ wqt, unsigned short* __restrict__ wkt,
    unsigned short* __restrict__ wvt, unsigned short* __restrict__ wot,
    unsigned short* __restrict__ wit, unsigned short* __restrict__ wo2t,
    const float* __restrict__ bq, const float* __restrict__ bk,
    const float* __restrict__ bv, float* __restrict__ bcat,
    const float* __restrict__ hid, unsigned short* __restrict__ hidb)
{
    __shared__ float tile[32][33];
    const int bid = blockIdx.x;
    const int tx = threadIdx.x, ty = threadIdx.y;

    if (bid < 6912) {
        const float* src; unsigned short* dst; int N, nx, local, NKT; float scale = 1.f;
        if (bid < 576)       { src = Wq;  dst = wqt;  N = 768;  nx = 24; local = bid;        NKT = 24; scale = 0.125f; }
        else if (bid < 1152) { src = Wk;  dst = wkt;  N = 768;  nx = 24; local = bid - 576;  NKT = 24; }
        else if (bid < 1728) { src = Wv;  dst = wvt;  N = 768;  nx = 24; local = bid - 1152; NKT = 24; }
        else if (bid < 2304) { src = Wo;  dst = wot;  N = 768;  nx = 24; local = bid - 1728; NKT = 24; }
        else if (bid < 4608) { src = Wi;  dst = wit;  N = 3072; nx = 96; local = bid - 2304; NKT = 24; }
        else                 { src = Wo2; dst = wo2t; N = 768;  nx = 24; local = bid - 4608; NKT = 96; }
        const int n0 = (local % nx) * 32, k0 = (local / nx) * 32;
#pragma unroll
        for (int i = 0; i < 4; ++i)
            tile[ty + 8 * i][tx] = src[(long)(k0 + ty + 8 * i) * N + n0 + tx];
        __syncthreads();
#pragma unroll
        for (int i = 0; i < 4; ++i) {
            const int nn = n0 + ty + 8 * i;
            const int kk = k0 + tx;
            const long fa = ((((long)(nn >> 7) * NKT + (kk >> 5)) * 8 + ((nn >> 4) & 7)) * 64
                             + ((kk >> 3) & 3) * 16 + (nn & 15)) * 8 + (kk & 7);
            dst[fa] = f2bf(tile[tx][ty + 8 * i] * scale);
        }
    } else if (bid < 6921) {
        const int t = ty * 32 + tx;
        const int i = (bid - 6912) * 256 + t;
        if (i < 768) bcat[i] = bq[i] * 0.125f;
        else if (i < 1536) bcat[i] = bk[i - 768];
        else if (i < 2304) bcat[i] = bv[i - 1536];
    } else {
        const int t = ty * 32 + tx;
        const long i = ((long)(bid - 6921) * 256 + t) * 4;
        float4 v = *(const float4*)(hid + i);
        ushort4 o;
        o.x = f2bf(v.x); o.y = f2bf(v.y); o.z = f2bf(v.z); o.w = f2bf(v.w);
        *(ushort4*)(hidb + i) = o;
    }
}

// ---------------------------------------------------------------------------
// V (B,NH,S,DH) bf16 -> Vt (B,NH,DH,S) bf16
// ---------------------------------------------------------------------------
__global__ __launch_bounds__(256) void vt_k(
    const unsigned short* __restrict__ v, unsigned short* __restrict__ vt)
{
    const int bh = blockIdx.y;
    const int s0 = blockIdx.x * 32;
    const int w = threadIdx.x >> 6, lane = threadIdx.x & 63;
    const unsigned short* src = v + ((long)bh * S_LEN + s0 + w * 8) * DH + lane;
    unsigned short r[8];
#pragma unroll
    for (int j = 0; j < 8; ++j) r[j] = src[j * DH];
    unsigned short* dst = vt + ((long)bh * DH + lane) * S_LEN + s0 + w * 8;
    ushort4 lo, hi;
    lo.x = r[0]; lo.y = r[1]; lo.z = r[2]; lo.w = r[3];
    hi.x = r[4]; hi.y = r[5]; hi.z = r[6]; hi.w = r[7];
    *(ushort4*)dst = lo;
    *(ushort4*)(dst + 4) = hi;
}

// ---------------------------------------------------------------------------
// bf16 MFMA GEMM v7: A LDS-staged (round-5 proven: 3-buffer, XOR swizzle,
// counted vmcnt, depth 2, unroll-6); B DIRECT from fragment-ordered weights
// (4 contiguous dwordx4 per wave per k-tile; uniform 8KB stride; zero LDS).
// n-MAJOR tile order (m0 = (t8&63)*128, n0 = (t8>>6)*128): with XCD-chunked
// swizzle each XCD sees <=3 B n-panels (<=1.2MB) -> B is L2-RESIDENT ->
// B load latency ~L2-hit, covered by one body (round-6 fix). A streams
// from L3 under the latency-tolerant gld_lds depth-2 pipeline.
// Per body U: issue 2 A-glds (t+2) + 4 B-frag loads (t+1) -> ds_read A ->
// 16 MFMA (B regs, compiler-waited) -> vmcnt(6) + s_barrier.
// Requires NT % 6 == 0 (24/24/12/48). LDS = 3 x 8 KiB.
// EPI 1: gelu -> bf16.  EPI 2: fused QKV scatter (Q scale pre-folded).
// ---------------------------------------------------------------------------
#define GB(U, BC, BN, PFA, PFB, WN)                                          \
    {                                                                        \
        if (PFA) {                                                           \
            async_copy16(aSrc0 + (U + 2) * 32, &As[(U + 2) % 3][g0]);        \
            async_copy16(aSrc1 + (U + 2) * 32, &As[(U + 2) % 3][g1]);        \
        }                                                                    \
        if (PFB) {                                                           \
            BN[0] = *(const bf16x8*)(bP + (U + 1) * 4096 + 0);               \
            BN[1] = *(const bf16x8*)(bP + (U + 1) * 4096 + 512);             \
            BN[2] = *(const bf16x8*)(bP + (U + 1) * 4096 + 1024);            \
            BN[3] = *(const bf16x8*)(bP + (U + 1) * 4096 + 1536);            \
        }                                                                    \
        __builtin_amdgcn_sched_barrier(0);                                   \
        bf16x8 af[4];                                                        \
        _Pragma("unroll")                                                    \
        for (int i = 0; i < 4; ++i)                                          \
            af[i] = *(const bf16x8*)&As[(U) % 3][rdA + i * 512];             \
        __builtin_amdgcn_s_setprio(1);                                       \
        _Pragma("unroll")                                                    \
        for (int i = 0; i < 4; ++i)                                          \
            _Pragma("unroll")                                                \
            for (int j = 0; j < 4; ++j)                                      \
                acc[i][j] = __builtin_amdgcn_mfma_f32_16x16x32_bf16(         \
                    af[i], BC[j], acc[i][j], 0, 0, 0);                       \
        __builtin_amdgcn_s_setprio(0);                                       \
        __builtin_amdgcn_sched_barrier(0);                                   \
        if (WN == 6) {                                                       \
            asm volatile("s_waitcnt vmcnt(6)" ::: "memory");                 \
            __builtin_amdgcn_s_barrier();                                    \
        } else if (WN == 4) {                                                \
            asm volatile("s_waitcnt vmcnt(4)" ::: "memory");                 \
            __builtin_amdgcn_s_barrier();                                    \
        }                                                                    \
        __builtin_amdgcn_sched_barrier(0);                                   \
    }

template <int EPI>
__global__ __launch_bounds__(256) void gemm_bf(
    const unsigned short* __restrict__ A, const unsigned short* __restrict__ BTf,
    const float* __restrict__ bias, void* __restrict__ out,
    int M, int N, int K, int nx)
{
    __shared__ unsigned short As[3][128 * 32];
    const int tid = threadIdx.x;
    const int wave = tid >> 6, lane = tid & 63;
    const int t8 = (blockIdx.x & 7) * (gridDim.x >> 3) + (blockIdx.x >> 3);
    const int m0 = (t8 & 63) * 128, n0 = (t8 >> 6) * 128;     // n-major
    const int wr = (wave >> 1) * 64, wc = (wave & 1) * 64;

    floatx4 acc[4][4];
#pragma unroll
    for (int i = 0; i < 4; ++i)
#pragma unroll
        for (int j = 0; j < 4; ++j) acc[i][j] = (floatx4){0.f, 0.f, 0.f, 0.f};

    const int srow = lane >> 2;
    const int schk = (((lane & 3) ^ (srow & 3))) * 8;   // XOR-swizzled A stage
    const int r = lane & 15, ln4 = lane >> 4;
    const int q8 = (ln4 ^ (lane & 3)) * 8;              // XOR-swizzled A read
    const int rdA = (wr + r) * 32 + q8;

    const int NT = K >> 5;                              // NT % 6 == 0
    const int NKT = K >> 5;
    const unsigned short* aSrc0 = A + (long)(m0 + wave * 32 + srow) * K + schk;
    const unsigned short* aSrc1 = A + (long)(m0 + wave * 32 + 16 + srow) * K + schk;
    const unsigned short* bP = BTf + (((long)(n0 >> 7) * NKT) << 12)
                                   + ((wc >> 4) << 9) + lane * 8;
    const int g0 = wave * 1024, g1 = wave * 1024 + 512;

    bf16x8 b0[4], b1[4];

    // prologue: A(0)->buf0, A(1)->buf1, B(0)->b0
    async_copy16(aSrc0, &As[0][g0]);
    async_copy16(aSrc1, &As[0][g1]);
    async_copy16(aSrc0 + 32, &As[1][g0]);
    async_copy16(aSrc1 + 32, &As[1][g1]);
    b0[0] = *(const bf16x8*)(bP + 0);
    b0[1] = *(const bf16x8*)(bP + 512);
    b0[2] = *(const bf16x8*)(bP + 1024);
    b0[3] = *(const bf16x8*)(bP + 1536);
    asm volatile("s_waitcnt vmcnt(6)" ::: "memory");
    __builtin_amdgcn_s_barrier();
    __builtin_amdgcn_sched_barrier(0);

    for (int t6 = 0; t6 < NT - 6; t6 += 6) {
        GB(0, b0, b1, 1, 1, 6)
        GB(1, b1, b0, 1, 1, 6)
        GB(2, b0, b1, 1, 1, 6)
        GB(3, b1, b0, 1, 1, 6)
        GB(4, b0, b1, 1, 1, 6)
        GB(5, b1, b0, 1, 1, 6)
        aSrc0 += 192; aSrc1 += 192; bP += 24576;
    }
    // tail macro (tiles NT-6 .. NT-1)
    GB(0, b0, b1, 1, 1, 6)
    GB(1, b1, b0, 1, 1, 6)
    GB(2, b0, b1, 1, 1, 6)
    GB(3, b1, b0, 1, 1, 6)
    GB(4, b0, b1, 0, 1, 4)
    GB(5, b1, b0, 0, 0, 0)

    const int col_l = lane & 15, row_l = (lane >> 4) * 4;
#pragma unroll
    for (int i = 0; i < 4; ++i) {
#pragma unroll
        for (int j = 0; j < 4; ++j) {
            const int n = n0 + wc + j * 16 + col_l;
            const float bv = bias[n];
#pragma unroll
            for (int rg = 0; rg < 4; ++rg) {
                const int m = m0 + wr + i * 16 + row_l + rg;
                float v = acc[i][j][rg] + bv;
                if (EPI == 1) {
                    v = 0.5f * v * (1.f + erff(v * 0.70710678118654752f));
                    ((unsigned short*)out)[(long)m * N + n] = f2bf(v);
                } else {
                    const int bb = m >> 12, s = m & 4095;
                    const int part = n / 768;          // 0=q, 1=k, 2=v
                    const int nn = n - part * 768;
                    const int hh = nn >> 6, dh = nn & 63;
                    ((unsigned short*)out)[(long)part * NQC +
                        (((long)bb * NHEAD + hh) * S_LEN + s) * DH + dh] = f2bf(v);
                }
            }
        }
    }
}

// ---------------------------------------------------------------------------
// Split-K (x2) bf16 MFMA GEMM, same A-LDS / B-frag-direct pipeline. Raw fp32
// partials; reduction happens inside ln2p_k.
// ---------------------------------------------------------------------------
__global__ __launch_bounds__(256) void gemm_sp(
    const unsigned short* __restrict__ A, const unsigned short* __restrict__ BTf,
    float* __restrict__ p0, float* __restrict__ p1,
    int M, int N, int K2, int nx, int ntile)
{
    __shared__ unsigned short As[3][128 * 32];
    const int tid = threadIdx.x;
    const int wave = tid >> 6, lane = tid & 63;
    const int t8 = (blockIdx.x & 7) * (gridDim.x >> 3) + (blockIdx.x >> 3);
    const int slice = t8 >= ntile;
    const int tile = t8 - slice * ntile;
    const int m0 = (tile & 63) * 128, n0 = (tile >> 6) * 128; // n-major
    const int kbeg = slice * K2;
    float* P = slice ? p1 : p0;
    const int wr = (wave >> 1) * 64, wc = (wave & 1) * 64;

    floatx4 acc[4][4];
#pragma unroll
    for (int i = 0; i < 4; ++i)
#pragma unroll
        for (int j = 0; j < 4; ++j) acc[i][j] = (floatx4){0.f, 0.f, 0.f, 0.f};

    const int srow = lane >> 2;
    const int schk = (((lane & 3) ^ (srow & 3))) * 8;
    const int r = lane & 15, ln4 = lane >> 4;
    const int q8 = (ln4 ^ (lane & 3)) * 8;
    const int rdA = (wr + r) * 32 + q8;
    const long Kl = (long)K2 * 2;

    const int NT = K2 >> 5;                             // NT % 6 == 0
    const int NKT = (int)(Kl >> 5);
    const int kt0 = kbeg >> 5;
    const unsigned short* aSrc0 = A + (long)(m0 + wave * 32 + srow) * Kl + kbeg + schk;
    const unsigned short* aSrc1 = A + (long)(m0 + wave * 32 + 16 + srow) * Kl + kbeg + schk;
    const unsigned short* bP = BTf + (((long)(n0 >> 7) * NKT + kt0) << 12)
                                   + ((wc >> 4) << 9) + lane * 8;
    const int g0 = wave * 1024, g1 = wave * 1024 + 512;

    bf16x8 b0[4], b1[4];

    async_copy16(aSrc0, &As[0][g0]);
    async_copy16(aSrc1, &As[0][g1]);
    async_copy16(aSrc0 + 32, &As[1][g0]);
    async_copy16(aSrc1 + 32, &As[1][g1]);
    b0[0] = *(const bf16x8*)(bP + 0);
    b0[1] = *(const bf16x8*)(bP + 512);
    b0[2] = *(const bf16x8*)(bP + 1024);
    b0[3] = *(const bf16x8*)(bP + 1536);
    asm volatile("s_waitcnt vmcnt(6)" ::: "memory");
    __builtin_amdgcn_s_barrier();
    __builtin_amdgcn_sched_barrier(0);

    for (int t6 = 0; t6 < NT - 6; t6 += 6) {
        GB(0, b0, b1, 1, 1, 6)
        GB(1, b1, b0, 1, 1, 6)
        GB(2, b0, b1, 1, 1, 6)
        GB(3, b1, b0, 1, 1, 6)
        GB(4, b0, b1, 1, 1, 6)
        GB(5, b1, b0, 1, 1, 6)
        aSrc0 += 192; aSrc1 += 192; bP += 24576;
    }
    GB(0, b0, b1, 1, 1, 6)
    GB(1, b1, b0, 1, 1, 6)
    GB(2, b0, b1, 1, 1, 6)
    GB(3, b1, b0, 1, 1, 6)
    GB(4, b0, b1, 0, 1, 4)
    GB(5, b1, b0, 0, 0, 0)

    const int col_l = lane & 15, row_l = (lane >> 4) * 4;
#pragma unroll
    for (int i = 0; i < 4; ++i)
#pragma unroll
        for (int j = 0; j < 4; ++j) {
            const int n = n0 + wc + j * 16 + col_l;
#pragma unroll
            for (int rg = 0; rg < 4; ++rg) {
                const int m = m0 + wr + i * 16 + row_l + rg;
                P[(long)m * N + n] = acc[i][j][rg];
            }
        }
}

// ---------------------------------------------------------------------------
// Fused attention: blocks [0,24) = global-query path (4 waves, 16 iters),
// blocks [24,792) = band path (b,h,chunk; 4 waves x 32 queries).
// Glob blocks launch FIRST so they overlap the band wave-front.
// Band suppresses stores for q0 < NGLB (those rows belong to glob) -> no race.
// ---------------------------------------------------------------------------
__global__ __launch_bounds__(256) void attn_k(
    const unsigned short* __restrict__ q, const unsigned short* __restrict__ k,
    const unsigned short* __restrict__ vt, const float* __restrict__ am,
    unsigned short* __restrict__ ctx)
{
    __shared__ __align__(16) unsigned char smem[28800];
    const int blk = blockIdx.x;
    const int tid = threadIdx.x;
    const int wave = tid >> 6, lane = tid & 63;
    const int ln15 = lane & 15, ln4 = lane >> 4;

    if (blk >= 24) {
        // ---------------- band path ----------------
        unsigned short* Ks = (unsigned short*)smem;            // 32*72
        unsigned short* Vs = Ks + 32 * 72;                     // 64*40
        unsigned short* Ps = Vs + 64 * 40;                     // [4][32*40]

        const int bb = blk - 24;
        const int c = bb & 31;
        const int h = (bb >> 5) % NHEAD;
        const int b = bb / (32 * NHEAD);
        const long bh = (long)b * NHEAD + h;

        const unsigned short* kh  = k + bh * S_LEN * DH;
        const unsigned short* vth = vt + bh * (long)DH * S_LEN;
        const float* amb = am + (long)b * S_LEN;

        const int q0 = c * WINSZ + wave * 32;

        bf16x8 qf[2][2];
#pragma unroll
        for (int nt = 0; nt < 2; ++nt)
#pragma unroll
            for (int ks = 0; ks < 2; ++ks)
                qf[nt][ks] = *(const bf16x8*)(q + (bh * S_LEN + q0 + nt * 16 + ln15) * DH
                                              + ks * 32 + ln4 * 8);

        floatx4 o[4][2];
#pragma unroll
        for (int mt = 0; mt < 4; ++mt)
#pragma unroll
            for (int nt = 0; nt < 2; ++nt) o[mt][nt] = (floatx4){0.f, 0.f, 0.f, 0.f};
        float m_r[2] = {-1e30f, -1e30f}, l_r[2] = {0.f, 0.f};

        const int sk_key = tid >> 3, sk_ch = tid & 7;
        const int sv_dim = tid & 63, sv_ch = tid >> 6;
        const bf16x8 zero8 = {0, 0, 0, 0, 0, 0, 0, 0};

        for (int tile = 0; tile < 13; ++tile) {
            const bool glob = (tile == 12);
            const int kbase = glob ? 0 : (c * WINSZ - WINSZ + tile * 32);

            __syncthreads();
            {
                int kpos = kbase + sk_key;
                bf16x8 val = zero8;
                if ((unsigned)kpos < (unsigned)S_LEN)
                    val = *(const bf16x8*)(kh + (long)kpos * DH + sk_ch * 8);
                *(bf16x8*)(&Ks[sk_key * 72 + sk_ch * 8]) = val;
            }
            {
                int kc = kbase + sv_ch * 8;
                bf16x8 val = zero8;
                if (kc >= 0 && kc + 8 <= S_LEN)
                    val = *(const bf16x8*)(vth + (long)sv_dim * S_LEN + kc);
                *(bf16x8*)(&Vs[sv_dim * 40 + sv_ch * 8]) = val;
            }
            __syncthreads();

            bf16x8 ak[2][2];
#pragma unroll
            for (int mt = 0; mt < 2; ++mt)
#pragma unroll
                for (int ks = 0; ks < 2; ++ks)
                    ak[mt][ks] = *(const bf16x8*)(&Ks[(mt * 16 + ln15) * 72 + ks * 32 + ln4 * 8]);

            floatx4 s[2][2];
#pragma unroll
            for (int mt = 0; mt < 2; ++mt)
#pragma unroll
                for (int nt = 0; nt < 2; ++nt) {
                    floatx4 acc = (floatx4){0.f, 0.f, 0.f, 0.f};
                    acc = __builtin_amdgcn_mfma_f32_16x16x32_bf16(ak[mt][0], qf[nt][0], acc, 0, 0, 0);
                    acc = __builtin_amdgcn_mfma_f32_16x16x32_bf16(ak[mt][1], qf[nt][1], acc, 0, 0, 0);
                    s[mt][nt] = acc;
                }

#pragma unroll
            for (int mt = 0; mt < 2; ++mt) {
                const int kp0 = kbase + mt * 16 + ln4 * 4;
#pragma unroll
                for (int rg = 0; rg < 4; ++rg) {
                    const int kpos = kp0 + rg;
                    const bool kin = (unsigned)kpos < (unsigned)S_LEN;
                    const float amv = kin ? amb[kpos] : 0.f;
#pragma unroll
                    for (int nt = 0; nt < 2; ++nt) {
                        const int qpos = q0 + nt * 16 + ln15;
                        const int dlt = kpos > qpos ? kpos - qpos : qpos - kpos;
                        const bool valid = glob || (kpos >= NGLB && kin && dlt <= WINSZ);
                        s[mt][nt][rg] = valid ? s[mt][nt][rg] + amv : NEGV;
                    }
                }
            }

            float alpha[2];
#pragma unroll
            for (int nt = 0; nt < 2; ++nt) {
                float mx = s[0][nt][0];
#pragma unroll
                for (int rg = 1; rg < 4; ++rg) mx = fmaxf(mx, s[0][nt][rg]);
#pragma unroll
                for (int rg = 0; rg < 4; ++rg) mx = fmaxf(mx, s[1][nt][rg]);
                mx = fmaxf(mx, __shfl_xor(mx, 16));
                mx = fmaxf(mx, __shfl_xor(mx, 32));
                const float mn = fmaxf(m_r[nt], mx);
                alpha[nt] = __expf(m_r[nt] - mn);
                m_r[nt] = mn;
            }

#pragma unroll
            for (int nt = 0; nt < 2; ++nt) {
                float sum = 0.f;
#pragma unroll
                for (int mt = 0; mt < 2; ++mt) {
                    ushort4 pk;
#pragma unroll
                    for (int rg = 0; rg < 4; ++rg) {
                        const float p = __expf(s[mt][nt][rg] - m_r[nt]);
                        sum += p;
                        ((unsigned short*)&pk)[rg] = f2bf(p);
                    }
                    *(ushort4*)(&Ps[wave * 1280 + (nt * 16 + ln15) * 40 + mt * 16 + ln4 * 4]) = pk;
                }
                sum += __shfl_xor(sum, 16);
                sum += __shfl_xor(sum, 32);
                l_r[nt] = l_r[nt] * alpha[nt] + sum;
            }

#pragma unroll
            for (int mt = 0; mt < 4; ++mt)
#pragma unroll
                for (int nt = 0; nt < 2; ++nt)
#pragma unroll
                    for (int rg = 0; rg < 4; ++rg) o[mt][nt][rg] *= alpha[nt];

            bf16x8 av[4], bp[2];
#pragma unroll
            for (int mt = 0; mt < 4; ++mt)
                av[mt] = *(const bf16x8*)(&Vs[(mt * 16 + ln15) * 40 + ln4 * 8]);
#pragma unroll
            for (int nt = 0; nt < 2; ++nt)
                bp[nt] = *(const bf16x8*)(&Ps[wave * 1280 + (nt * 16 + ln15) * 40 + ln4 * 8]);
#pragma unroll
            for (int mt = 0; mt < 4; ++mt)
#pragma unroll
                for (int nt = 0; nt < 2; ++nt)
                    o[mt][nt] = __builtin_amdgcn_mfma_f32_16x16x32_bf16(
                        av[mt], bp[nt], o[mt][nt], 0, 0, 0);
        }

        if (q0 >= NGLB) {
            const float inv0 = 1.f / l_r[0], inv1 = 1.f / l_r[1];
#pragma unroll
            for (int nt = 0; nt < 2; ++nt) {
                const float inv = nt ? inv1 : inv0;
                const long row = (long)b * S_LEN + q0 + nt * 16 + ln15;
#pragma unroll
                for (int mt = 0; mt < 4; ++mt) {
                    ushort4 ov;
#pragma unroll
                    for (int rg = 0; rg < 4; ++rg)
                        ((unsigned short*)&ov)[rg] = f2bf(o[mt][nt][rg] * inv);
                    *(ushort4*)(ctx + row * D_MODEL + h * DH + mt * 16 + ln4 * 4) = ov;
                }
            }
        }
    } else {
        // ---------------- global-query path (4 waves, 16 iters) ----------------
        unsigned short* Psg = (unsigned short*)smem;           // [4][32*72]
        float* Om   = (float*)(smem + 18432);                  // 64*36
        float* mW   = (float*)(smem + 27648);                  // [4][32]
        float* lW   = (float*)(smem + 28160);                  // [4][32]
        float* lTot = (float*)(smem + 28672);                  // [32]

        const int bh = blk;
        const int b = bh / NHEAD, h = bh % NHEAD;

        const unsigned short* kh  = k + (long)bh * S_LEN * DH;
        const unsigned short* vth = vt + (long)bh * DH * S_LEN;
        const float* amb = am + (long)b * S_LEN;

        bf16x8 qf[2][2];
#pragma unroll
        for (int nt = 0; nt < 2; ++nt)
#pragma unroll
            for (int ks = 0; ks < 2; ++ks)
                qf[nt][ks] = *(const bf16x8*)(q + ((long)bh * S_LEN + nt * 16 + ln15) * DH
                                              + ks * 32 + ln4 * 8);

        floatx4 o[4][2];
#pragma unroll
        for (int mt = 0; mt < 4; ++mt)
#pragma unroll
            for (int nt = 0; nt < 2; ++nt) o[mt][nt] = (floatx4){0.f, 0.f, 0.f, 0.f};
        float m_r[2] = {-1e30f, -1e30f}, l_r[2] = {0.f, 0.f};

        for (int it = 0; it < 16; ++it) {
            const int kbase = it * 256 + wave * 64;

            bf16x8 ak[4][2];
#pragma unroll
            for (int mt = 0; mt < 4; ++mt)
#pragma unroll
                for (int ks = 0; ks < 2; ++ks)
                    ak[mt][ks] = *(const bf16x8*)(kh + (long)(kbase + mt * 16 + ln15) * DH
                                                  + ks * 32 + ln4 * 8);

            floatx4 s[4][2];
#pragma unroll
            for (int mt = 0; mt < 4; ++mt)
#pragma unroll
                for (int nt = 0; nt < 2; ++nt) {
                    floatx4 acc = (floatx4){0.f, 0.f, 0.f, 0.f};
                    acc = __builtin_amdgcn_mfma_f32_16x16x32_bf16(ak[mt][0], qf[nt][0], acc, 0, 0, 0);
                    acc = __builtin_amdgcn_mfma_f32_16x16x32_bf16(ak[mt][1], qf[nt][1], acc, 0, 0, 0);
                    s[mt][nt] = acc;
                }

#pragma unroll
            for (int mt = 0; mt < 4; ++mt) {
                const int kp0 = kbase + mt * 16 + ln4 * 4;
#pragma unroll
                for (int rg = 0; rg < 4; ++rg) {
                    const float amv = amb[kp0 + rg];
#pragma unroll
                    for (int nt = 0; nt < 2; ++nt) s[mt][nt][rg] += amv;
                }
            }

            float alpha[2];
#pragma unroll
            for (int nt = 0; nt < 2; ++nt) {
                float mx = s[0][nt][0];
#pragma unroll
                for (int mt = 0; mt < 4; ++mt)
#pragma unroll
                    for (int rg = 0; rg < 4; ++rg) mx = fmaxf(mx, s[mt][nt][rg]);
                mx = fmaxf(mx, __shfl_xor(mx, 16));
                mx = fmaxf(mx, __shfl_xor(mx, 32));
                const float mn = fmaxf(m_r[nt], mx);
                alpha[nt] = __expf(m_r[nt] - mn);
                m_r[nt] = mn;
            }

#pragma unroll
            for (int nt = 0; nt < 2; ++nt) {
                float sum = 0.f;
#pragma unroll
                for (int mt = 0; mt < 4; ++mt) {
                    ushort4 pk;
#pragma unroll
                    for (int rg = 0; rg < 4; ++rg) {
                        const float p = __expf(s[mt][nt][rg] - m_r[nt]);
                        sum += p;
                        ((unsigned short*)&pk)[rg] = f2bf(p);
                    }
                    *(ushort4*)(&Psg[wave * 2304 + (nt * 16 + ln15) * 72 + mt * 16 + ln4 * 4]) = pk;
                }
                sum += __shfl_xor(sum, 16);
                sum += __shfl_xor(sum, 32);
                l_r[nt] = l_r[nt] * alpha[nt] + sum;
            }

#pragma unroll
            for (int mt = 0; mt < 4; ++mt)
#pragma unroll
                for (int nt = 0; nt < 2; ++nt)
#pragma unroll
                    for (int rg = 0; rg < 4; ++rg) o[mt][nt][rg] *= alpha[nt];

            bf16x8 av[4][2], bp[2][2];
#pragma unroll
            for (int mt = 0; mt < 4; ++mt)
#pragma unroll
                for (int ks = 0; ks < 2; ++ks)
                    av[mt][ks] = *(const bf16x8*)(vth + (long)(mt * 16 + ln15) * S_LEN
                                                  + kbase + ks * 32 + ln4 * 8);
#pragma unroll
            for (int nt = 0; nt < 2; ++nt)
#pragma unroll
                for (int ks = 0; ks < 2; ++ks)
                    bp[nt][ks] = *(const bf16x8*)(&Psg[wave * 2304 + (nt * 16 + ln15) * 72
                                                  + ks * 32 + ln4 * 8]);
#pragma unroll
            for (int mt = 0; mt < 4; ++mt)
#pragma unroll
                for (int nt = 0; nt < 2; ++nt) {
                    o[mt][nt] = __builtin_amdgcn_mfma_f32_16x16x32_bf16(
                        av[mt][0], bp[nt][0], o[mt][nt], 0, 0, 0);
                    o[mt][nt] = __builtin_amdgcn_mfma_f32_16x16x32_bf16(
                        av[mt][1], bp[nt][1], o[mt][nt], 0, 0, 0);
                }
        }

        if (ln4 == 0) {
#pragma unroll
            for (int nt = 0; nt < 2; ++nt) {
                mW[wave * 32 + nt * 16 + ln15] = m_r[nt];
                lW[wave * 32 + nt * 16 + ln15] = l_r[nt];
            }
        }
        for (int i = tid; i < 64 * 36; i += 256) Om[i] = 0.f;
        __syncthreads();

        float f[2];
#pragma unroll
        for (int nt = 0; nt < 2; ++nt) {
            const int qq = nt * 16 + ln15;
            float mt_ = mW[qq];
#pragma unroll
            for (int w = 1; w < 4; ++w) mt_ = fmaxf(mt_, mW[w * 32 + qq]);
            float lt = 0.f;
#pragma unroll
            for (int w = 0; w < 4; ++w) lt += __expf(mW[w * 32 + qq] - mt_) * lW[w * 32 + qq];
            f[nt] = __expf(m_r[nt] - mt_);
            if (wave == 0 && ln4 == 0) lTot[qq] = lt;
        }
#pragma unroll
        for (int mt = 0; mt < 4; ++mt)
#pragma unroll
            for (int nt = 0; nt < 2; ++nt)
#pragma unroll
                for (int rg = 0; rg < 4; ++rg) o[mt][nt][rg] *= f[nt];

        for (int wv = 0; wv < 4; ++wv) {
            if (wave == wv) {
#pragma unroll
                for (int mt = 0; mt < 4; ++mt)
#pragma unroll
                    for (int nt = 0; nt < 2; ++nt)
#pragma unroll
                        for (int rg = 0; rg < 4; ++rg)
                            Om[(mt * 16 + ln4 * 4 + rg) * 36 + nt * 16 + ln15] += o[mt][nt][rg];
            }
            __syncthreads();
        }

        const int qq = tid >> 3, d0 = (tid & 7) * 8;
        const float inv = 1.f / lTot[qq];
        ushort4 ov0, ov1;
#pragma unroll
        for (int i = 0; i < 4; ++i)
            ((unsigned short*)&ov0)[i] = f2bf(Om[(d0 + i) * 36 + qq] * inv);
#pragma unroll
        for (int i = 0; i < 4; ++i)
            ((unsigned short*)&ov1)[i] = f2bf(Om[(d0 + 4 + i) * 36 + qq] * inv);
        unsigned short* dst = ctx + ((long)b * S_LEN + qq) * D_MODEL + h * DH + d0;
        *(ushort4*)dst = ov0;
        *(ushort4*)(dst + 4) = ov1;
    }
}

// ---------------------------------------------------------------------------
// Fused split-K reduce + bias + residual + LayerNorm. x = p0+p1+bias+resid.
// One block per row (768 cols). Shfl wave-reduce (2 syncs, not 16).
// ---------------------------------------------------------------------------
__global__ __launch_bounds__(256) void ln2p_k(
    const float* __restrict__ p0, const float* __restrict__ p1,
    const float* __restrict__ bias, const float* __restrict__ resid,
    float* __restrict__ out, unsigned short* __restrict__ out_bf,
    const float* __restrict__ gw, const float* __restrict__ bw)
{
    __shared__ float red[8];
    const long base = (long)blockIdx.x * D_MODEL;
    const int t = threadIdx.x;
    const int wv = t >> 6, lane = t & 63;
    float v0 = p0[base + t]       + p1[base + t]       + bias[t]       + resid[base + t];
    float v1 = p0[base + t + 256] + p1[base + t + 256] + bias[t + 256] + resid[base + t + 256];
    float v2 = p0[base + t + 512] + p1[base + t + 512] + bias[t + 512] + resid[base + t + 512];

    float s = v0 + v1 + v2;
#pragma unroll
    for (int off = 32; off; off >>= 1) s += __shfl_xor(s, off);
    if (lane == 0) red[wv] = s;
    __syncthreads();
    const float mu = (red[0] + red[1] + red[2] + red[3]) * (1.f / 768.f);

    const float d0 = v0 - mu, d1 = v1 - mu, d2 = v2 - mu;
    float s2 = d0 * d0 + d1 * d1 + d2 * d2;
#pragma unroll
    for (int off = 32; off; off >>= 1) s2 += __shfl_xor(s2, off);
    if (lane == 0) red[4 + wv] = s2;
    __syncthreads();
    const float var = (red[4] + red[5] + red[6] + red[7]) * (1.f / 768.f);
    const float rs = rsqrtf(var + 1e-12f);

    const float y0 = d0 * rs * gw[t] + bw[t];
    const float y1 = d1 * rs * gw[t + 256] + bw[t + 256];
    const float y2 = d2 * rs * gw[t + 512] + bw[t + 512];
    if (out) {
        float* y = out + base;
        y[t] = y0; y[t + 256] = y1; y[t + 512] = y2;
    }
    if (out_bf) {
        unsigned short* yb = out_bf + base;
        yb[t] = f2bf(y0); yb[t + 256] = f2bf(y1); yb[t + 512] = f2bf(y2);
    }
}

// ---------------------------------------------------------------------------
extern "C" void kernel_launch(void* const* d_in, const int* in_sizes, int n_in,
                              void* d_out, int out_size, void* d_ws, size_t ws_size,
                              hipStream_t stream)
{
    const float* hid  = (const float*)d_in[0];
    const float* am   = (const float*)d_in[1];
    const float* Wq   = (const float*)d_in[2];
    const float* bq   = (const float*)d_in[3];
    const float* Wk   = (const float*)d_in[4];
    const float* bk   = (const float*)d_in[5];
    const float* Wv   = (const float*)d_in[6];
    const float* bv   = (const float*)d_in[7];
    const float* Wo   = (const float*)d_in[8];
    const float* bo   = (const float*)d_in[9];
    const float* ln1g = (const float*)d_in[10];
    const float* ln1b = (const float*)d_in[11];
    const float* Wi   = (const float*)d_in[12];
    const float* bi   = (const float*)d_in[13];
    const float* Wo2  = (const float*)d_in[14];
    const float* bo2  = (const float*)d_in[15];
    const float* ln2g = (const float*)d_in[16];
    const float* ln2b = (const float*)d_in[17];

    const long M  = (long)B_SZ * S_LEN;                 // 8192
    const long NQ = NQC;                                // 6291456

    unsigned short* W16 = (unsigned short*)d_ws;
    unsigned short* qb   = W16;             // bf16 (B,NH,S,DH) — q|k|v contiguous
    unsigned short* kb   = W16 + NQ;
    unsigned short* vb   = W16 + 2 * NQ;
    unsigned short* vtb  = W16 + 3 * NQ;    // bf16 (B,NH,DH,S)
    unsigned short* ctxb = W16 + 4 * NQ;    // bf16 (B,S,768)
    unsigned short* hidb = W16 + 5 * NQ;    // bf16 hidden
    unsigned short* wqt  = W16 + 6 * NQ;    // frag-order [Wq|Wk|Wv] 2304x768
    unsigned short* wkt  = wqt + 589824;
    unsigned short* wvt  = wkt + 589824;
    unsigned short* wot  = wvt + 589824;
    unsigned short* wit  = wot + 589824;    // 2359296
    unsigned short* wo2t = wit + 2359296;   // 2359296 -> ends at u16 44826624
    float* tmp   = (float*)(W16 + 44826624);  // attn_out fp32 -> ends u16 57409536
    float* partB1 = (float*)(W16 + 57409536); // Wo2 split slice1 -> ends u16 69992448
    float* bcat  = (float*)(W16 + 69992448);  // 2304 fp32
    // aliases over dead regions:
    float* partA0 = (float*)W16;                  // Wo slice0 (over qb,kb)
    float* partA1 = (float*)(W16 + 2 * NQ);       // Wo slice1 (over vb,vtb)
    unsigned short* interb = W16;                 // Wi out (over qb..vtb)
    unsigned short* attnb  = hidb;                // LN1 bf16 (over hidb)
    float* partB0 = (float*)(W16 + 4 * NQ);       // Wo2 slice0 (over ctxb,hidb)
    (void)ws_size; (void)in_sizes; (void)n_in; (void)out_size;

    // fused prep: 6 frag-order transposes (+0.125 into Wq) + bcat + conv
    prep_k<<<dim3(13065), dim3(32, 8), 0, stream>>>(
        Wq, Wk, Wv, Wo, Wi, Wo2, wqt, wkt, wvt, wot, wit, wo2t,
        bq, bk, bv, bcat, hid, hidb);

    dim3 blk(256);

    // fused QKV: one GEMM, N = 2304, scatter to qb/kb/vb
    gemm_bf<2><<<dim3(1152), blk, 0, stream>>>(hidb, wqt, bcat, qb,
                                               M, 2304, 768, 18);

    vt_k<<<dim3(128, 24), blk, 0, stream>>>(vb, vtb);

    // fused band + global attention (glob blocks first for overlap)
    attn_k<<<dim3(792), blk, 0, stream>>>(qb, kb, vtb, am, ctxb);

    // Wo split-K x2 -> partA0/partA1 ; LN1 fuses reduce+bias+resid
    gemm_sp<<<dim3(768), blk, 0, stream>>>(ctxb, wot, partA0, partA1,
                                           M, 768, 384, 6, 384);
    ln2p_k<<<dim3(M), blk, 0, stream>>>(partA0, partA1, bo, hid,
                                        tmp, attnb, ln1g, ln1b);

    // inter = gelu(attn_out @ Wi + bi)
    gemm_bf<1><<<dim3(1536), blk, 0, stream>>>(attnb, wit, bi, interb,
                                               M, 3072, 768, 24);

    // Wo2 split-K x2 -> partB0/partB1 ; LN2 fuses reduce+bias+resid
    gemm_sp<<<dim3(768), blk, 0, stream>>>(interb, wo2t, partB0, partB1,
                                           M, 768, 1536, 6, 384);
    ln2p_k<<<dim3(M), blk, 0, stream>>>(partB0, partB1, bo2, tmp,
                                        (float*)d_out, nullptr, ln2g, ln2b);
}

// Round 8
// 407.115 us; speedup vs baseline: 1.2689x; 1.0305x over previous
//
#include <hip/hip_runtime.h>
#include <math.h>

#define NHEAD 12
#define DH 64
#define S_LEN 4096
#define B_SZ 2
#define D_MODEL 768
#define FF_DIM 3072
#define WINSZ 128
#define NGLB 32
#define NEGV -1e9f
#define NQC 6291456L

typedef __attribute__((ext_vector_type(8))) short bf16x8;
typedef __attribute__((ext_vector_type(4))) float floatx4;

__device__ __forceinline__ unsigned short f2bf(float x) {
    union { float f; unsigned u; } v; v.f = x;
    unsigned r = v.u + 0x7fffu + ((v.u >> 16) & 1u);
    return (unsigned short)(r >> 16);
}
__device__ __forceinline__ float bf2f(unsigned short x) {
    union { unsigned u; float f; } v; v.u = ((unsigned)x) << 16;
    return v.f;
}

__device__ __forceinline__ void async_copy16(const unsigned short* g, unsigned short* l) {
    __builtin_amdgcn_global_load_lds(
        (const __attribute__((address_space(1))) void*)g,
        (__attribute__((address_space(3))) void*)l, 16, 0, 0);
}

// ---------------------------------------------------------------------------
// Fused prep: 6 weight transposes (fp32 KxN -> bf16 NxK, Wq scaled 0.125)
// + bias concat (bq scaled 0.125) + hidden fp32->bf16 conversion.
// Block ranges: [0,6912) transposes, [6912,6921) bcat, [6921,13065) conv.
// ---------------------------------------------------------------------------
__global__ __launch_bounds__(256) void prep_k(
    const float* __restrict__ Wq, const float* __restrict__ Wk,
    const float* __restrict__ Wv, const float* __restrict__ Wo,
    const float* __restrict__ Wi, const float* __restrict__ Wo2,
    unsigned short* __restrict__ wqt, unsigned short* __restrict__ wkt,
    unsigned short* __restrict__ wvt, unsigned short* __restrict__ wot,
    unsigned short* __restrict__ wit, unsigned short* __restrict__ wo2t,
    const float* __restrict__ bq, const float* __restrict__ bk,
    const float* __restrict__ bv, float* __restrict__ bcat,
    const float* __restrict__ hid, unsigned short* __restrict__ hidb)
{
    __shared__ float tile[32][33];
    const int bid = blockIdx.x;
    const int tx = threadIdx.x, ty = threadIdx.y;

    if (bid < 6912) {
        const float* src; unsigned short* dst; int K, N, nx, local; float scale = 1.f;
        if (bid < 576)       { src = Wq;  dst = wqt;  K = 768;  N = 768;  nx = 24; local = bid;        scale = 0.125f; }
        else if (bid < 1152) { src = Wk;  dst = wkt;  K = 768;  N = 768;  nx = 24; local = bid - 576;  }
        else if (bid < 1728) { src = Wv;  dst = wvt;  K = 768;  N = 768;  nx = 24; local = bid - 1152; }
        else if (bid < 2304) { src = Wo;  dst = wot;  K = 768;  N = 768;  nx = 24; local = bid - 1728; }
        else if (bid < 4608) { src = Wi;  dst = wit;  K = 768;  N = 3072; nx = 96; local = bid - 2304; }
        else                 { src = Wo2; dst = wo2t; K = 3072; N = 768;  nx = 24; local = bid - 4608; }
        const int n0 = (local % nx) * 32, k0 = (local / nx) * 32;
#pragma unroll
        for (int i = 0; i < 4; ++i)
            tile[ty + 8 * i][tx] = src[(long)(k0 + ty + 8 * i) * N + n0 + tx];
        __syncthreads();
#pragma unroll
        for (int i = 0; i < 4; ++i)
            dst[(long)(n0 + ty + 8 * i) * K + k0 + tx] = f2bf(tile[tx][ty + 8 * i] * scale);
    } else if (bid < 6921) {
        const int t = ty * 32 + tx;
        const int i = (bid - 6912) * 256 + t;
        if (i < 768) bcat[i] = bq[i] * 0.125f;
        else if (i < 1536) bcat[i] = bk[i - 768];
        else if (i < 2304) bcat[i] = bv[i - 1536];
    } else {
        const int t = ty * 32 + tx;
        const long i = ((long)(bid - 6921) * 256 + t) * 4;
        float4 v = *(const float4*)(hid + i);
        ushort4 o;
        o.x = f2bf(v.x); o.y = f2bf(v.y); o.z = f2bf(v.z); o.w = f2bf(v.w);
        *(ushort4*)(hidb + i) = o;
    }
}

// ---------------------------------------------------------------------------
// V (B,NH,S,DH) bf16 -> Vt (B,NH,DH,S) bf16
// ---------------------------------------------------------------------------
__global__ __launch_bounds__(256) void vt_k(
    const unsigned short* __restrict__ v, unsigned short* __restrict__ vt)
{
    const int bh = blockIdx.y;
    const int s0 = blockIdx.x * 32;
    const int w = threadIdx.x >> 6, lane = threadIdx.x & 63;
    const unsigned short* src = v + ((long)bh * S_LEN + s0 + w * 8) * DH + lane;
    unsigned short r[8];
#pragma unroll
    for (int j = 0; j < 8; ++j) r[j] = src[j * DH];
    unsigned short* dst = vt + ((long)bh * DH + lane) * S_LEN + s0 + w * 8;
    ushort4 lo, hi;
    lo.x = r[0]; lo.y = r[1]; lo.z = r[2]; lo.w = r[3];
    hi.x = r[4]; hi.y = r[5]; hi.z = r[6]; hi.w = r[7];
    *(ushort4*)dst = lo;
    *(ushort4*)(dst + 4) = hi;
}

// ---------------------------------------------------------------------------
// bf16 MFMA GEMM (round-5 proven structure: 3-buffer / depth-2 counted-vmcnt
// pipeline, K-loop unrolled by 3 for compile-time buffer indices).
// Body u: prefetch buf (u+2)%3, ds_read+MFMA buf u, vmcnt(4)+s_barrier.
// Tail macro: body0 prefetches tile NT-1 (vmcnt(4)); body1 vmcnt(0);
// body2 no trailing wait. Requires NT % 3 == 0 (holds: 24/24/12/48).
// EPI 1: bias+gelu -> bf16
// EPI 2: fused QKV scatter: part=n/768 (q|k|v) -> bf16 (Q scale pre-folded)
// EPI 3: bias + residual (fp32 resid ptr) -> fp32 (pre-LN value; no split-K)
// ---------------------------------------------------------------------------
#define GEMM_BODY(U, PF, TAILW)                                              \
    {                                                                        \
        if (PF) {                                                            \
            async_copy16(aSrc0 + (U + 2) * 32, &As[(U + 2) % 3][g0]);        \
            async_copy16(bSrc0 + (U + 2) * 32, &Bs[(U + 2) % 3][g0]);        \
            async_copy16(aSrc1 + (U + 2) * 32, &As[(U + 2) % 3][g1]);        \
            async_copy16(bSrc1 + (U + 2) * 32, &Bs[(U + 2) % 3][g1]);        \
        }                                                                    \
        __builtin_amdgcn_sched_barrier(0);                                   \
        bf16x8 af[4], bfr[4];                                                \
        _Pragma("unroll")                                                    \
        for (int i = 0; i < 4; ++i) {                                        \
            af[i]  = *(const bf16x8*)&As[U][rdA + i * 512];                  \
            bfr[i] = *(const bf16x8*)&Bs[U][rdB + i * 512];                  \
        }                                                                    \
        __builtin_amdgcn_s_setprio(1);                                       \
        _Pragma("unroll")                                                    \
        for (int i = 0; i < 4; ++i)                                          \
            _Pragma("unroll")                                                \
            for (int j = 0; j < 4; ++j)                                      \
                acc[i][j] = __builtin_amdgcn_mfma_f32_16x16x32_bf16(         \
                    af[i], bfr[j], acc[i][j], 0, 0, 0);                      \
        __builtin_amdgcn_s_setprio(0);                                       \
        __builtin_amdgcn_sched_barrier(0);                                   \
        if (TAILW == 2) {                                                    \
            asm volatile("s_waitcnt vmcnt(4)" ::: "memory");                 \
            __builtin_amdgcn_s_barrier();                                    \
        } else if (TAILW == 1) {                                             \
            asm volatile("s_waitcnt vmcnt(0)" ::: "memory");                 \
            __builtin_amdgcn_s_barrier();                                    \
        }                                                                    \
        __builtin_amdgcn_sched_barrier(0);                                   \
    }

template <int EPI>
__global__ __launch_bounds__(256) void gemm_bf(
    const unsigned short* __restrict__ A, const unsigned short* __restrict__ BT,
    const float* __restrict__ bias, void* __restrict__ out,
    int M, int N, int K, int nx, const float* __restrict__ resid)
{
    __shared__ unsigned short As[3][128 * 32];
    __shared__ unsigned short Bs[3][128 * 32];
    const int tid = threadIdx.x;
    const int wave = tid >> 6, lane = tid & 63;
    const int t8 = (blockIdx.x & 7) * (gridDim.x >> 3) + (blockIdx.x >> 3);
    const int m0 = (t8 / nx) * 128, n0 = (t8 % nx) * 128;
    const int wr = (wave >> 1) * 64, wc = (wave & 1) * 64;

    floatx4 acc[4][4];
#pragma unroll
    for (int i = 0; i < 4; ++i)
#pragma unroll
        for (int j = 0; j < 4; ++j) acc[i][j] = (floatx4){0.f, 0.f, 0.f, 0.f};

    const int srow = lane >> 2;
    const int schk = (((lane & 3) ^ (srow & 3))) * 8;   // XOR-swizzled stage
    const int r = lane & 15;
    const int q8 = ((lane >> 4) ^ (lane & 3)) * 8;      // XOR-swizzled read
    const int rdA = (wr + r) * 32 + q8;                 // static ds_read bases
    const int rdB = (wc + r) * 32 + q8;

    const int NT = K >> 5;                              // NT % 3 == 0
    const unsigned short* aSrc0 = A  + (long)(m0 + wave * 32 + srow) * K + schk;
    const unsigned short* aSrc1 = A  + (long)(m0 + wave * 32 + 16 + srow) * K + schk;
    const unsigned short* bSrc0 = BT + (long)(n0 + wave * 32 + srow) * K + schk;
    const unsigned short* bSrc1 = BT + (long)(n0 + wave * 32 + 16 + srow) * K + schk;
    const int g0 = wave * 1024, g1 = wave * 1024 + 512;

    // prologue: stage tiles 0 and 1 into bufs 0 and 1
    async_copy16(aSrc0, &As[0][g0]);
    async_copy16(bSrc0, &Bs[0][g0]);
    async_copy16(aSrc1, &As[0][g1]);
    async_copy16(bSrc1, &Bs[0][g1]);
    async_copy16(aSrc0 + 32, &As[1][g0]);
    async_copy16(bSrc0 + 32, &Bs[1][g0]);
    async_copy16(aSrc1 + 32, &As[1][g1]);
    async_copy16(bSrc1 + 32, &Bs[1][g1]);
    asm volatile("s_waitcnt vmcnt(4)" ::: "memory");
    __builtin_amdgcn_s_barrier();
    __builtin_amdgcn_sched_barrier(0);

    for (int t3 = 0; t3 < NT - 3; t3 += 3) {
        GEMM_BODY(0, 1, 2)
        GEMM_BODY(1, 1, 2)
        GEMM_BODY(2, 1, 2)
        aSrc0 += 96; aSrc1 += 96; bSrc0 += 96; bSrc1 += 96;
    }
    // tail macro-iter (t3 == NT-3): body0 prefetches tile NT-1
    GEMM_BODY(0, 1, 2)
    GEMM_BODY(1, 0, 1)
    GEMM_BODY(2, 0, 0)

    const int col_l = lane & 15, row_l = (lane >> 4) * 4;
#pragma unroll
    for (int i = 0; i < 4; ++i) {
#pragma unroll
        for (int j = 0; j < 4; ++j) {
            const int n = n0 + wc + j * 16 + col_l;
            const float bv = bias[n];
#pragma unroll
            for (int rg = 0; rg < 4; ++rg) {
                const int m = m0 + wr + i * 16 + row_l + rg;
                float v = acc[i][j][rg] + bv;
                if (EPI == 1) {
                    v = 0.5f * v * (1.f + erff(v * 0.70710678118654752f));
                    ((unsigned short*)out)[(long)m * N + n] = f2bf(v);
                } else if (EPI == 3) {
                    ((float*)out)[(long)m * N + n] = v + resid[(long)m * N + n];
                } else {
                    const int bb = m >> 12, s = m & 4095;
                    const int part = n / 768;          // 0=q, 1=k, 2=v
                    const int nn = n - part * 768;
                    const int hh = nn >> 6, dh = nn & 63;
                    ((unsigned short*)out)[(long)part * NQC +
                        (((long)bb * NHEAD + hh) * S_LEN + s) * DH + dh] = f2bf(v);
                }
            }
        }
    }
}

// ---------------------------------------------------------------------------
// Split-K (x2) bf16 MFMA GEMM, same unrolled 3-buffer pipeline. Raw fp32
// partials; reduction happens inside ln2p_k. (Kept for Wo2: K=3072.)
// ---------------------------------------------------------------------------
__global__ __launch_bounds__(256) void gemm_sp(
    const unsigned short* __restrict__ A, const unsigned short* __restrict__ BT,
    float* __restrict__ p0, float* __restrict__ p1,
    int M, int N, int K2, int nx, int ntile)
{
    __shared__ unsigned short As[3][128 * 32];
    __shared__ unsigned short Bs[3][128 * 32];
    const int tid = threadIdx.x;
    const int wave = tid >> 6, lane = tid & 63;
    const int t8 = (blockIdx.x & 7) * (gridDim.x >> 3) + (blockIdx.x >> 3);
    const int slice = t8 >= ntile;
    const int tile = t8 - slice * ntile;
    const int m0 = (tile / nx) * 128, n0 = (tile % nx) * 128;
    const int kbeg = slice * K2;
    float* P = slice ? p1 : p0;
    const int wr = (wave >> 1) * 64, wc = (wave & 1) * 64;

    floatx4 acc[4][4];
#pragma unroll
    for (int i = 0; i < 4; ++i)
#pragma unroll
        for (int j = 0; j < 4; ++j) acc[i][j] = (floatx4){0.f, 0.f, 0.f, 0.f};

    const int srow = lane >> 2;
    const int schk = (((lane & 3) ^ (srow & 3))) * 8;
    const int r = lane & 15;
    const int q8 = ((lane >> 4) ^ (lane & 3)) * 8;
    const int rdA = (wr + r) * 32 + q8;
    const int rdB = (wc + r) * 32 + q8;
    const long Kl = (long)K2 * 2;

    const int NT = K2 >> 5;                             // NT % 3 == 0
    const unsigned short* aSrc0 = A  + (long)(m0 + wave * 32 + srow) * Kl + kbeg + schk;
    const unsigned short* aSrc1 = A  + (long)(m0 + wave * 32 + 16 + srow) * Kl + kbeg + schk;
    const unsigned short* bSrc0 = BT + (long)(n0 + wave * 32 + srow) * Kl + kbeg + schk;
    const unsigned short* bSrc1 = BT + (long)(n0 + wave * 32 + 16 + srow) * Kl + kbeg + schk;
    const int g0 = wave * 1024, g1 = wave * 1024 + 512;

    async_copy16(aSrc0, &As[0][g0]);
    async_copy16(bSrc0, &Bs[0][g0]);
    async_copy16(aSrc1, &As[0][g1]);
    async_copy16(bSrc1, &Bs[0][g1]);
    async_copy16(aSrc0 + 32, &As[1][g0]);
    async_copy16(bSrc0 + 32, &Bs[1][g0]);
    async_copy16(aSrc1 + 32, &As[1][g1]);
    async_copy16(bSrc1 + 32, &Bs[1][g1]);
    asm volatile("s_waitcnt vmcnt(4)" ::: "memory");
    __builtin_amdgcn_s_barrier();
    __builtin_amdgcn_sched_barrier(0);

    for (int t3 = 0; t3 < NT - 3; t3 += 3) {
        GEMM_BODY(0, 1, 2)
        GEMM_BODY(1, 1, 2)
        GEMM_BODY(2, 1, 2)
        aSrc0 += 96; aSrc1 += 96; bSrc0 += 96; bSrc1 += 96;
    }
    GEMM_BODY(0, 1, 2)
    GEMM_BODY(1, 0, 1)
    GEMM_BODY(2, 0, 0)

    const int col_l = lane & 15, row_l = (lane >> 4) * 4;
#pragma unroll
    for (int i = 0; i < 4; ++i)
#pragma unroll
        for (int j = 0; j < 4; ++j) {
            const int n = n0 + wc + j * 16 + col_l;
#pragma unroll
            for (int rg = 0; rg < 4; ++rg) {
                const int m = m0 + wr + i * 16 + row_l + rg;
                P[(long)m * N + n] = acc[i][j][rg];
            }
        }
}

// ---------------------------------------------------------------------------
// Fused attention: blocks [0,24) = global-query path (4 waves, 16 iters),
// blocks [24,792) = band path (b,h,chunk; 4 waves x 32 queries).
// Glob blocks launch FIRST so they overlap the band wave-front.
// Band suppresses stores for q0 < NGLB (those rows belong to glob) -> no race.
// ---------------------------------------------------------------------------
__global__ __launch_bounds__(256) void attn_k(
    const unsigned short* __restrict__ q, const unsigned short* __restrict__ k,
    const unsigned short* __restrict__ vt, const float* __restrict__ am,
    unsigned short* __restrict__ ctx)
{
    __shared__ __align__(16) unsigned char smem[28800];
    const int blk = blockIdx.x;
    const int tid = threadIdx.x;
    const int wave = tid >> 6, lane = tid & 63;
    const int ln15 = lane & 15, ln4 = lane >> 4;

    if (blk >= 24) {
        // ---------------- band path ----------------
        unsigned short* Ks = (unsigned short*)smem;            // 32*72
        unsigned short* Vs = Ks + 32 * 72;                     // 64*40
        unsigned short* Ps = Vs + 64 * 40;                     // [4][32*40]

        const int bb = blk - 24;
        const int c = bb & 31;
        const int h = (bb >> 5) % NHEAD;
        const int b = bb / (32 * NHEAD);
        const long bh = (long)b * NHEAD + h;

        const unsigned short* kh  = k + bh * S_LEN * DH;
        const unsigned short* vth = vt + bh * (long)DH * S_LEN;
        const float* amb = am + (long)b * S_LEN;

        const int q0 = c * WINSZ + wave * 32;

        bf16x8 qf[2][2];
#pragma unroll
        for (int nt = 0; nt < 2; ++nt)
#pragma unroll
            for (int ks = 0; ks < 2; ++ks)
                qf[nt][ks] = *(const bf16x8*)(q + (bh * S_LEN + q0 + nt * 16 + ln15) * DH
                                              + ks * 32 + ln4 * 8);

        floatx4 o[4][2];
#pragma unroll
        for (int mt = 0; mt < 4; ++mt)
#pragma unroll
            for (int nt = 0; nt < 2; ++nt) o[mt][nt] = (floatx4){0.f, 0.f, 0.f, 0.f};
        float m_r[2] = {-1e30f, -1e30f}, l_r[2] = {0.f, 0.f};

        const int sk_key = tid >> 3, sk_ch = tid & 7;
        const int sv_dim = tid & 63, sv_ch = tid >> 6;
        const bf16x8 zero8 = {0, 0, 0, 0, 0, 0, 0, 0};

        for (int tile = 0; tile < 13; ++tile) {
            const bool glob = (tile == 12);
            const int kbase = glob ? 0 : (c * WINSZ - WINSZ + tile * 32);

            __syncthreads();
            {
                int kpos = kbase + sk_key;
                bf16x8 val = zero8;
                if ((unsigned)kpos < (unsigned)S_LEN)
                    val = *(const bf16x8*)(kh + (long)kpos * DH + sk_ch * 8);
                *(bf16x8*)(&Ks[sk_key * 72 + sk_ch * 8]) = val;
            }
            {
                int kc = kbase + sv_ch * 8;
                bf16x8 val = zero8;
                if (kc >= 0 && kc + 8 <= S_LEN)
                    val = *(const bf16x8*)(vth + (long)sv_dim * S_LEN + kc);
                *(bf16x8*)(&Vs[sv_dim * 40 + sv_ch * 8]) = val;
            }
            __syncthreads();

            bf16x8 ak[2][2];
#pragma unroll
            for (int mt = 0; mt < 2; ++mt)
#pragma unroll
                for (int ks = 0; ks < 2; ++ks)
                    ak[mt][ks] = *(const bf16x8*)(&Ks[(mt * 16 + ln15) * 72 + ks * 32 + ln4 * 8]);

            floatx4 s[2][2];
#pragma unroll
            for (int mt = 0; mt < 2; ++mt)
#pragma unroll
                for (int nt = 0; nt < 2; ++nt) {
                    floatx4 acc = (floatx4){0.f, 0.f, 0.f, 0.f};
                    acc = __builtin_amdgcn_mfma_f32_16x16x32_bf16(ak[mt][0], qf[nt][0], acc, 0, 0, 0);
                    acc = __builtin_amdgcn_mfma_f32_16x16x32_bf16(ak[mt][1], qf[nt][1], acc, 0, 0, 0);
                    s[mt][nt] = acc;
                }

#pragma unroll
            for (int mt = 0; mt < 2; ++mt) {
                const int kp0 = kbase + mt * 16 + ln4 * 4;
#pragma unroll
                for (int rg = 0; rg < 4; ++rg) {
                    const int kpos = kp0 + rg;
                    const bool kin = (unsigned)kpos < (unsigned)S_LEN;
                    const float amv = kin ? amb[kpos] : 0.f;
#pragma unroll
                    for (int nt = 0; nt < 2; ++nt) {
                        const int qpos = q0 + nt * 16 + ln15;
                        const int dlt = kpos > qpos ? kpos - qpos : qpos - kpos;
                        const bool valid = glob || (kpos >= NGLB && kin && dlt <= WINSZ);
                        s[mt][nt][rg] = valid ? s[mt][nt][rg] + amv : NEGV;
                    }
                }
            }

            float alpha[2];
#pragma unroll
            for (int nt = 0; nt < 2; ++nt) {
                float mx = s[0][nt][0];
#pragma unroll
                for (int rg = 1; rg < 4; ++rg) mx = fmaxf(mx, s[0][nt][rg]);
#pragma unroll
                for (int rg = 0; rg < 4; ++rg) mx = fmaxf(mx, s[1][nt][rg]);
                mx = fmaxf(mx, __shfl_xor(mx, 16));
                mx = fmaxf(mx, __shfl_xor(mx, 32));
                const float mn = fmaxf(m_r[nt], mx);
                alpha[nt] = __expf(m_r[nt] - mn);
                m_r[nt] = mn;
            }

#pragma unroll
            for (int nt = 0; nt < 2; ++nt) {
                float sum = 0.f;
#pragma unroll
                for (int mt = 0; mt < 2; ++mt) {
                    ushort4 pk;
#pragma unroll
                    for (int rg = 0; rg < 4; ++rg) {
                        const float p = __expf(s[mt][nt][rg] - m_r[nt]);
                        sum += p;
                        ((unsigned short*)&pk)[rg] = f2bf(p);
                    }
                    *(ushort4*)(&Ps[wave * 1280 + (nt * 16 + ln15) * 40 + mt * 16 + ln4 * 4]) = pk;
                }
                sum += __shfl_xor(sum, 16);
                sum += __shfl_xor(sum, 32);
                l_r[nt] = l_r[nt] * alpha[nt] + sum;
            }

#pragma unroll
            for (int mt = 0; mt < 4; ++mt)
#pragma unroll
                for (int nt = 0; nt < 2; ++nt)
#pragma unroll
                    for (int rg = 0; rg < 4; ++rg) o[mt][nt][rg] *= alpha[nt];

            bf16x8 av[4], bp[2];
#pragma unroll
            for (int mt = 0; mt < 4; ++mt)
                av[mt] = *(const bf16x8*)(&Vs[(mt * 16 + ln15) * 40 + ln4 * 8]);
#pragma unroll
            for (int nt = 0; nt < 2; ++nt)
                bp[nt] = *(const bf16x8*)(&Ps[wave * 1280 + (nt * 16 + ln15) * 40 + ln4 * 8]);
#pragma unroll
            for (int mt = 0; mt < 4; ++mt)
#pragma unroll
                for (int nt = 0; nt < 2; ++nt)
                    o[mt][nt] = __builtin_amdgcn_mfma_f32_16x16x32_bf16(
                        av[mt], bp[nt], o[mt][nt], 0, 0, 0);
        }

        if (q0 >= NGLB) {
            const float inv0 = 1.f / l_r[0], inv1 = 1.f / l_r[1];
#pragma unroll
            for (int nt = 0; nt < 2; ++nt) {
                const float inv = nt ? inv1 : inv0;
                const long row = (long)b * S_LEN + q0 + nt * 16 + ln15;
#pragma unroll
                for (int mt = 0; mt < 4; ++mt) {
                    ushort4 ov;
#pragma unroll
                    for (int rg = 0; rg < 4; ++rg)
                        ((unsigned short*)&ov)[rg] = f2bf(o[mt][nt][rg] * inv);
                    *(ushort4*)(ctx + row * D_MODEL + h * DH + mt * 16 + ln4 * 4) = ov;
                }
            }
        }
    } else {
        // ---------------- global-query path (4 waves, 16 iters) ----------------
        unsigned short* Psg = (unsigned short*)smem;           // [4][32*72]
        float* Om   = (float*)(smem + 18432);                  // 64*36
        float* mW   = (float*)(smem + 27648);                  // [4][32]
        float* lW   = (float*)(smem + 28160);                  // [4][32]
        float* lTot = (float*)(smem + 28672);                  // [32]

        const int bh = blk;
        const int b = bh / NHEAD, h = bh % NHEAD;

        const unsigned short* kh  = k + (long)bh * S_LEN * DH;
        const unsigned short* vth = vt + (long)bh * DH * S_LEN;
        const float* amb = am + (long)b * S_LEN;

        bf16x8 qf[2][2];
#pragma unroll
        for (int nt = 0; nt < 2; ++nt)
#pragma unroll
            for (int ks = 0; ks < 2; ++ks)
                qf[nt][ks] = *(const bf16x8*)(q + ((long)bh * S_LEN + nt * 16 + ln15) * DH
                                              + ks * 32 + ln4 * 8);

        floatx4 o[4][2];
#pragma unroll
        for (int mt = 0; mt < 4; ++mt)
#pragma unroll
            for (int nt = 0; nt < 2; ++nt) o[mt][nt] = (floatx4){0.f, 0.f, 0.f, 0.f};
        float m_r[2] = {-1e30f, -1e30f}, l_r[2] = {0.f, 0.f};

        for (int it = 0; it < 16; ++it) {
            const int kbase = it * 256 + wave * 64;

            bf16x8 ak[4][2];
#pragma unroll
            for (int mt = 0; mt < 4; ++mt)
#pragma unroll
                for (int ks = 0; ks < 2; ++ks)
                    ak[mt][ks] = *(const bf16x8*)(kh + (long)(kbase + mt * 16 + ln15) * DH
                                                  + ks * 32 + ln4 * 8);

            floatx4 s[4][2];
#pragma unroll
            for (int mt = 0; mt < 4; ++mt)
#pragma unroll
                for (int nt = 0; nt < 2; ++nt) {
                    floatx4 acc = (floatx4){0.f, 0.f, 0.f, 0.f};
                    acc = __builtin_amdgcn_mfma_f32_16x16x32_bf16(ak[mt][0], qf[nt][0], acc, 0, 0, 0);
                    acc = __builtin_amdgcn_mfma_f32_16x16x32_bf16(ak[mt][1], qf[nt][1], acc, 0, 0, 0);
                    s[mt][nt] = acc;
                }

#pragma unroll
            for (int mt = 0; mt < 4; ++mt) {
                const int kp0 = kbase + mt * 16 + ln4 * 4;
#pragma unroll
                for (int rg = 0; rg < 4; ++rg) {
                    const float amv = amb[kp0 + rg];
#pragma unroll
                    for (int nt = 0; nt < 2; ++nt) s[mt][nt][rg] += amv;
                }
            }

            float alpha[2];
#pragma unroll
            for (int nt = 0; nt < 2; ++nt) {
                float mx = s[0][nt][0];
#pragma unroll
                for (int mt = 0; mt < 4; ++mt)
#pragma unroll
                    for (int rg = 0; rg < 4; ++rg) mx = fmaxf(mx, s[mt][nt][rg]);
                mx = fmaxf(mx, __shfl_xor(mx, 16));
                mx = fmaxf(mx, __shfl_xor(mx, 32));
                const float mn = fmaxf(m_r[nt], mx);
                alpha[nt] = __expf(m_r[nt] - mn);
                m_r[nt] = mn;
            }

#pragma unroll
            for (int nt = 0; nt < 2; ++nt) {
                float sum = 0.f;
#pragma unroll
                for (int mt = 0; mt < 4; ++mt) {
                    ushort4 pk;
#pragma unroll
                    for (int rg = 0; rg < 4; ++rg) {
                        const float p = __expf(s[mt][nt][rg] - m_r[nt]);
                        sum += p;
                        ((unsigned short*)&pk)[rg] = f2bf(p);
                    }
                    *(ushort4*)(&Psg[wave * 2304 + (nt * 16 + ln15) * 72 + mt * 16 + ln4 * 4]) = pk;
                }
                sum += __shfl_xor(sum, 16);
                sum += __shfl_xor(sum, 32);
                l_r[nt] = l_r[nt] * alpha[nt] + sum;
            }

#pragma unroll
            for (int mt = 0; mt < 4; ++mt)
#pragma unroll
                for (int nt = 0; nt < 2; ++nt)
#pragma unroll
                    for (int rg = 0; rg < 4; ++rg) o[mt][nt][rg] *= alpha[nt];

            bf16x8 av[4][2], bp[2][2];
#pragma unroll
            for (int mt = 0; mt < 4; ++mt)
#pragma unroll
                for (int ks = 0; ks < 2; ++ks)
                    av[mt][ks] = *(const bf16x8*)(vth + (long)(mt * 16 + ln15) * S_LEN
                                                  + kbase + ks * 32 + ln4 * 8);
#pragma unroll
            for (int nt = 0; nt < 2; ++nt)
#pragma unroll
                for (int ks = 0; ks < 2; ++ks)
                    bp[nt][ks] = *(const bf16x8*)(&Psg[wave * 2304 + (nt * 16 + ln15) * 72
                                                  + ks * 32 + ln4 * 8]);
#pragma unroll
            for (int mt = 0; mt < 4; ++mt)
#pragma unroll
                for (int nt = 0; nt < 2; ++nt) {
                    o[mt][nt] = __builtin_amdgcn_mfma_f32_16x16x32_bf16(
                        av[mt][0], bp[nt][0], o[mt][nt], 0, 0, 0);
                    o[mt][nt] = __builtin_amdgcn_mfma_f32_16x16x32_bf16(
                        av[mt][1], bp[nt][1], o[mt][nt], 0, 0, 0);
                }
        }

        if (ln4 == 0) {
#pragma unroll
            for (int nt = 0; nt < 2; ++nt) {
                mW[wave * 32 + nt * 16 + ln15] = m_r[nt];
                lW[wave * 32 + nt * 16 + ln15] = l_r[nt];
            }
        }
        for (int i = tid; i < 64 * 36; i += 256) Om[i] = 0.f;
        __syncthreads();

        float f[2];
#pragma unroll
        for (int nt = 0; nt < 2; ++nt) {
            const int qq = nt * 16 + ln15;
            float mt_ = mW[qq];
#pragma unroll
            for (int w = 1; w < 4; ++w) mt_ = fmaxf(mt_, mW[w * 32 + qq]);
            float lt = 0.f;
#pragma unroll
            for (int w = 0; w < 4; ++w) lt += __expf(mW[w * 32 + qq] - mt_) * lW[w * 32 + qq];
            f[nt] = __expf(m_r[nt] - mt_);
            if (wave == 0 && ln4 == 0) lTot[qq] = lt;
        }
#pragma unroll
        for (int mt = 0; mt < 4; ++mt)
#pragma unroll
            for (int nt = 0; nt < 2; ++nt)
#pragma unroll
                for (int rg = 0; rg < 4; ++rg) o[mt][nt][rg] *= f[nt];

        for (int wv = 0; wv < 4; ++wv) {
            if (wave == wv) {
#pragma unroll
                for (int mt = 0; mt < 4; ++mt)
#pragma unroll
                    for (int nt = 0; nt < 2; ++nt)
#pragma unroll
                        for (int rg = 0; rg < 4; ++rg)
                            Om[(mt * 16 + ln4 * 4 + rg) * 36 + nt * 16 + ln15] += o[mt][nt][rg];
            }
            __syncthreads();
        }

        const int qq = tid >> 3, d0 = (tid & 7) * 8;
        const float inv = 1.f / lTot[qq];
        ushort4 ov0, ov1;
#pragma unroll
        for (int i = 0; i < 4; ++i)
            ((unsigned short*)&ov0)[i] = f2bf(Om[(d0 + i) * 36 + qq] * inv);
#pragma unroll
        for (int i = 0; i < 4; ++i)
            ((unsigned short*)&ov1)[i] = f2bf(Om[(d0 + 4 + i) * 36 + qq] * inv);
        unsigned short* dst = ctx + ((long)b * S_LEN + qq) * D_MODEL + h * DH + d0;
        *(ushort4*)dst = ov0;
        *(ushort4*)(dst + 4) = ov1;
    }
}

// ---------------------------------------------------------------------------
// Fused reduce + LayerNorm. x = p0 [+ p1] [+ bias] [+ resid] (null-skippable).
// One block per row (768 cols). Shfl wave-reduce (2 syncs).
// ---------------------------------------------------------------------------
__global__ __launch_bounds__(256) void ln2p_k(
    const float* __restrict__ p0, const float* __restrict__ p1,
    const float* __restrict__ bias, const float* __restrict__ resid,
    float* __restrict__ out, unsigned short* __restrict__ out_bf,
    const float* __restrict__ gw, const float* __restrict__ bw)
{
    __shared__ float red[8];
    const long base = (long)blockIdx.x * D_MODEL;
    const int t = threadIdx.x;
    const int wv = t >> 6, lane = t & 63;
    float v0 = p0[base + t];
    float v1 = p0[base + t + 256];
    float v2 = p0[base + t + 512];
    if (p1) {
        v0 += p1[base + t]; v1 += p1[base + t + 256]; v2 += p1[base + t + 512];
    }
    if (bias) {
        v0 += bias[t]; v1 += bias[t + 256]; v2 += bias[t + 512];
    }
    if (resid) {
        v0 += resid[base + t]; v1 += resid[base + t + 256]; v2 += resid[base + t + 512];
    }

    float s = v0 + v1 + v2;
#pragma unroll
    for (int off = 32; off; off >>= 1) s += __shfl_xor(s, off);
    if (lane == 0) red[wv] = s;
    __syncthreads();
    const float mu = (red[0] + red[1] + red[2] + red[3]) * (1.f / 768.f);

    const float d0 = v0 - mu, d1 = v1 - mu, d2 = v2 - mu;
    float s2 = d0 * d0 + d1 * d1 + d2 * d2;
#pragma unroll
    for (int off = 32; off; off >>= 1) s2 += __shfl_xor(s2, off);
    if (lane == 0) red[4 + wv] = s2;
    __syncthreads();
    const float var = (red[4] + red[5] + red[6] + red[7]) * (1.f / 768.f);
    const float rs = rsqrtf(var + 1e-12f);

    const float y0 = d0 * rs * gw[t] + bw[t];
    const float y1 = d1 * rs * gw[t + 256] + bw[t + 256];
    const float y2 = d2 * rs * gw[t + 512] + bw[t + 512];
    if (out) {
        float* y = out + base;
        y[t] = y0; y[t + 256] = y1; y[t + 512] = y2;
    }
    if (out_bf) {
        unsigned short* yb = out_bf + base;
        yb[t] = f2bf(y0); yb[t + 256] = f2bf(y1); yb[t + 512] = f2bf(y2);
    }
}

// ---------------------------------------------------------------------------
extern "C" void kernel_launch(void* const* d_in, const int* in_sizes, int n_in,
                              void* d_out, int out_size, void* d_ws, size_t ws_size,
                              hipStream_t stream)
{
    const float* hid  = (const float*)d_in[0];
    const float* am   = (const float*)d_in[1];
    const float* Wq   = (const float*)d_in[2];
    const float* bq   = (const float*)d_in[3];
    const float* Wk   = (const float*)d_in[4];
    const float* bk   = (const float*)d_in[5];
    const float* Wv   = (const float*)d_in[6];
    const float* bv   = (const float*)d_in[7];
    const float* Wo   = (const float*)d_in[8];
    const float* bo   = (const float*)d_in[9];
    const float* ln1g = (const float*)d_in[10];
    const float* ln1b = (const float*)d_in[11];
    const float* Wi   = (const float*)d_in[12];
    const float* bi   = (const float*)d_in[13];
    const float* Wo2  = (const float*)d_in[14];
    const float* bo2  = (const float*)d_in[15];
    const float* ln2g = (const float*)d_in[16];
    const float* ln2b = (const float*)d_in[17];

    const long M  = (long)B_SZ * S_LEN;                 // 8192
    const long NQ = NQC;                                // 6291456

    unsigned short* W16 = (unsigned short*)d_ws;
    unsigned short* qb   = W16;             // bf16 (B,NH,S,DH) — q|k|v contiguous
    unsigned short* kb   = W16 + NQ;
    unsigned short* vb   = W16 + 2 * NQ;
    unsigned short* vtb  = W16 + 3 * NQ;    // bf16 (B,NH,DH,S)
    unsigned short* ctxb = W16 + 4 * NQ;    // bf16 (B,S,768)
    unsigned short* hidb = W16 + 5 * NQ;    // bf16 hidden
    unsigned short* wqt  = W16 + 6 * NQ;    // [Wq|Wk|Wv]^T contiguous 2304x768
    unsigned short* wkt  = wqt + 589824;
    unsigned short* wvt  = wkt + 589824;
    unsigned short* wot  = wvt + 589824;
    unsigned short* wit  = wot + 589824;    // 2359296
    unsigned short* wo2t = wit + 2359296;   // 2359296 -> ends at u16 44826624
    float* tmp   = (float*)(W16 + 44826624);  // attn_out fp32 -> ends u16 57409536
    float* partB1 = (float*)(W16 + 57409536); // Wo2 split slice1 -> ends u16 69992448
    float* bcat  = (float*)(W16 + 69992448);  // 2304 fp32
    // aliases over dead regions:
    float* zA = (float*)W16;                      // Wo pre-LN fp32 (over qb,kb)
    unsigned short* interb = W16;                 // Wi out (over qb..vtb)
    unsigned short* attnb  = hidb;                // LN1 bf16 (over hidb)
    float* partB0 = (float*)(W16 + 4 * NQ);       // Wo2 slice0 (over ctxb,hidb)
    (void)ws_size; (void)in_sizes; (void)n_in; (void)out_size;

    // fused prep: 6 transposes (+0.125 fold into Wq) + bcat (+0.125 bq) + conv
    prep_k<<<dim3(13065), dim3(32, 8), 0, stream>>>(
        Wq, Wk, Wv, Wo, Wi, Wo2, wqt, wkt, wvt, wot, wit, wo2t,
        bq, bk, bv, bcat, hid, hidb);

    dim3 blk(256);

    // fused QKV: one GEMM, N = 2304, scatter to qb/kb/vb
    gemm_bf<2><<<dim3(1152), blk, 0, stream>>>(hidb, wqt, bcat, qb,
                                               M, 2304, 768, 18, nullptr);

    vt_k<<<dim3(128, 24), blk, 0, stream>>>(vb, vtb);

    // fused band + global attention (glob blocks first for overlap)
    attn_k<<<dim3(792), blk, 0, stream>>>(qb, kb, vtb, am, ctxb);

    // Wo: no split-K (K=768). Epilogue fuses +bo +hid -> fp32 zA; then LN1.
    gemm_bf<3><<<dim3(384), blk, 0, stream>>>(ctxb, wot, bo, zA,
                                              M, 768, 768, 6, hid);
    ln2p_k<<<dim3(M), blk, 0, stream>>>(zA, nullptr, nullptr, nullptr,
                                        tmp, attnb, ln1g, ln1b);

    // inter = gelu(attn_out @ Wi + bi)
    gemm_bf<1><<<dim3(1536), blk, 0, stream>>>(attnb, wit, bi, interb,
                                               M, 3072, 768, 24, nullptr);

    // Wo2 split-K x2 -> partB0/partB1 ; LN2 fuses reduce+bias+resid
    gemm_sp<<<dim3(768), blk, 0, stream>>>(interb, wo2t, partB0, partB1,
                                           M, 768, 1536, 6, 384);
    ln2p_k<<<dim3(M), blk, 0, stream>>>(partB0, partB1, bo2, tmp,
                                        (float*)d_out, nullptr, ln2g, ln2b);
}

// Round 9
// 395.756 us; speedup vs baseline: 1.3053x; 1.0287x over previous
//
#include <hip/hip_runtime.h>
#include <math.h>

#define NHEAD 12
#define DH 64
#define S_LEN 4096
#define B_SZ 2
#define D_MODEL 768
#define FF_DIM 3072
#define WINSZ 128
#define NGLB 32
#define NEGV -1e9f
#define NQC 6291456L

typedef __attribute__((ext_vector_type(8))) short bf16x8;
typedef __attribute__((ext_vector_type(4))) float floatx4;

__device__ __forceinline__ unsigned short f2bf(float x) {
    union { float f; unsigned u; } v; v.f = x;
    unsigned r = v.u + 0x7fffu + ((v.u >> 16) & 1u);
    return (unsigned short)(r >> 16);
}
__device__ __forceinline__ float bf2f(unsigned short x) {
    union { unsigned u; float f; } v; v.u = ((unsigned)x) << 16;
    return v.f;
}

__device__ __forceinline__ void async_copy16(const unsigned short* g, unsigned short* l) {
    __builtin_amdgcn_global_load_lds(
        (const __attribute__((address_space(1))) void*)g,
        (__attribute__((address_space(3))) void*)l, 16, 0, 0);
}

// ---------------------------------------------------------------------------
// Fused prep: 6 weight transposes (fp32 KxN -> bf16 NxK, Wq scaled 0.125)
// + bias concat (bq scaled 0.125) + hidden fp32->bf16 conversion.
// Block ranges: [0,6912) transposes, [6912,6921) bcat, [6921,13065) conv.
// ---------------------------------------------------------------------------
__global__ __launch_bounds__(256) void prep_k(
    const float* __restrict__ Wq, const float* __restrict__ Wk,
    const float* __restrict__ Wv, const float* __restrict__ Wo,
    const float* __restrict__ Wi, const float* __restrict__ Wo2,
    unsigned short* __restrict__ wqt, unsigned short* __restrict__ wkt,
    unsigned short* __restrict__ wvt, unsigned short* __restrict__ wot,
    unsigned short* __restrict__ wit, unsigned short* __restrict__ wo2t,
    const float* __restrict__ bq, const float* __restrict__ bk,
    const float* __restrict__ bv, float* __restrict__ bcat,
    const float* __restrict__ hid, unsigned short* __restrict__ hidb)
{
    __shared__ float tile[32][33];
    const int bid = blockIdx.x;
    const int tx = threadIdx.x, ty = threadIdx.y;

    if (bid < 6912) {
        const float* src; unsigned short* dst; int K, N, nx, local; float scale = 1.f;
        if (bid < 576)       { src = Wq;  dst = wqt;  K = 768;  N = 768;  nx = 24; local = bid;        scale = 0.125f; }
        else if (bid < 1152) { src = Wk;  dst = wkt;  K = 768;  N = 768;  nx = 24; local = bid - 576;  }
        else if (bid < 1728) { src = Wv;  dst = wvt;  K = 768;  N = 768;  nx = 24; local = bid - 1152; }
        else if (bid < 2304) { src = Wo;  dst = wot;  K = 768;  N = 768;  nx = 24; local = bid - 1728; }
        else if (bid < 4608) { src = Wi;  dst = wit;  K = 768;  N = 3072; nx = 96; local = bid - 2304; }
        else                 { src = Wo2; dst = wo2t; K = 3072; N = 768;  nx = 24; local = bid - 4608; }
        const int n0 = (local % nx) * 32, k0 = (local / nx) * 32;
#pragma unroll
        for (int i = 0; i < 4; ++i)
            tile[ty + 8 * i][tx] = src[(long)(k0 + ty + 8 * i) * N + n0 + tx];
        __syncthreads();
#pragma unroll
        for (int i = 0; i < 4; ++i)
            dst[(long)(n0 + ty + 8 * i) * K + k0 + tx] = f2bf(tile[tx][ty + 8 * i] * scale);
    } else if (bid < 6921) {
        const int t = ty * 32 + tx;
        const int i = (bid - 6912) * 256 + t;
        if (i < 768) bcat[i] = bq[i] * 0.125f;
        else if (i < 1536) bcat[i] = bk[i - 768];
        else if (i < 2304) bcat[i] = bv[i - 1536];
    } else {
        const int t = ty * 32 + tx;
        const long i = ((long)(bid - 6921) * 256 + t) * 4;
        float4 v = *(const float4*)(hid + i);
        ushort4 o;
        o.x = f2bf(v.x); o.y = f2bf(v.y); o.z = f2bf(v.z); o.w = f2bf(v.w);
        *(ushort4*)(hidb + i) = o;
    }
}

// ---------------------------------------------------------------------------
// bf16 MFMA GEMM (round-5 proven structure: 3-buffer / depth-2 counted-vmcnt
// pipeline, K-loop unrolled by 3 for compile-time buffer indices).
// Body u: prefetch buf (u+2)%3, ds_read+MFMA buf u, vmcnt(4)+s_barrier.
// Tail macro: body0 prefetches tile NT-1 (vmcnt(4)); body1 vmcnt(0);
// body2 no trailing wait. Requires NT % 3 == 0 (holds: 24/24/12/48).
// EPI 1: bias+gelu -> bf16
// EPI 2: fused QKV scatter: q/k -> (B,NH,S,DH); V written TRANSPOSED to
//        out2 (B,NH,DH,S) as ushort4 (rg spans 4 consecutive s) -> vt_k gone
// EPI 3: bias + residual (fp32 resid ptr) -> fp32 (pre-LN value; no split-K)
// ---------------------------------------------------------------------------
#define GEMM_BODY(U, PF, TAILW)                                              \
    {                                                                        \
        if (PF) {                                                            \
            async_copy16(aSrc0 + (U + 2) * 32, &As[(U + 2) % 3][g0]);        \
            async_copy16(bSrc0 + (U + 2) * 32, &Bs[(U + 2) % 3][g0]);        \
            async_copy16(aSrc1 + (U + 2) * 32, &As[(U + 2) % 3][g1]);        \
            async_copy16(bSrc1 + (U + 2) * 32, &Bs[(U + 2) % 3][g1]);        \
        }                                                                    \
        __builtin_amdgcn_sched_barrier(0);                                   \
        bf16x8 af[4], bfr[4];                                                \
        _Pragma("unroll")                                                    \
        for (int i = 0; i < 4; ++i) {                                        \
            af[i]  = *(const bf16x8*)&As[U][rdA + i * 512];                  \
            bfr[i] = *(const bf16x8*)&Bs[U][rdB + i * 512];                  \
        }                                                                    \
        __builtin_amdgcn_s_setprio(1);                                       \
        _Pragma("unroll")                                                    \
        for (int i = 0; i < 4; ++i)                                          \
            _Pragma("unroll")                                                \
            for (int j = 0; j < 4; ++j)                                      \
                acc[i][j] = __builtin_amdgcn_mfma_f32_16x16x32_bf16(         \
                    af[i], bfr[j], acc[i][j], 0, 0, 0);                      \
        __builtin_amdgcn_s_setprio(0);                                       \
        __builtin_amdgcn_sched_barrier(0);                                   \
        if (TAILW == 2) {                                                    \
            asm volatile("s_waitcnt vmcnt(4)" ::: "memory");                 \
            __builtin_amdgcn_s_barrier();                                    \
        } else if (TAILW == 1) {                                             \
            asm volatile("s_waitcnt vmcnt(0)" ::: "memory");                 \
            __builtin_amdgcn_s_barrier();                                    \
        }                                                                    \
        __builtin_amdgcn_sched_barrier(0);                                   \
    }

template <int EPI>
__global__ __launch_bounds__(256) void gemm_bf(
    const unsigned short* __restrict__ A, const unsigned short* __restrict__ BT,
    const float* __restrict__ bias, void* __restrict__ out,
    int M, int N, int K, int nx, const float* __restrict__ resid,
    unsigned short* __restrict__ out2)
{
    __shared__ unsigned short As[3][128 * 32];
    __shared__ unsigned short Bs[3][128 * 32];
    const int tid = threadIdx.x;
    const int wave = tid >> 6, lane = tid & 63;
    const int t8 = (blockIdx.x & 7) * (gridDim.x >> 3) + (blockIdx.x >> 3);
    const int m0 = (t8 / nx) * 128, n0 = (t8 % nx) * 128;
    const int wr = (wave >> 1) * 64, wc = (wave & 1) * 64;

    floatx4 acc[4][4];
#pragma unroll
    for (int i = 0; i < 4; ++i)
#pragma unroll
        for (int j = 0; j < 4; ++j) acc[i][j] = (floatx4){0.f, 0.f, 0.f, 0.f};

    const int srow = lane >> 2;
    const int schk = (((lane & 3) ^ (srow & 3))) * 8;   // XOR-swizzled stage
    const int r = lane & 15;
    const int q8 = ((lane >> 4) ^ (lane & 3)) * 8;      // XOR-swizzled read
    const int rdA = (wr + r) * 32 + q8;                 // static ds_read bases
    const int rdB = (wc + r) * 32 + q8;

    const int NT = K >> 5;                              // NT % 3 == 0
    const unsigned short* aSrc0 = A  + (long)(m0 + wave * 32 + srow) * K + schk;
    const unsigned short* aSrc1 = A  + (long)(m0 + wave * 32 + 16 + srow) * K + schk;
    const unsigned short* bSrc0 = BT + (long)(n0 + wave * 32 + srow) * K + schk;
    const unsigned short* bSrc1 = BT + (long)(n0 + wave * 32 + 16 + srow) * K + schk;
    const int g0 = wave * 1024, g1 = wave * 1024 + 512;

    // prologue: stage tiles 0 and 1 into bufs 0 and 1
    async_copy16(aSrc0, &As[0][g0]);
    async_copy16(bSrc0, &Bs[0][g0]);
    async_copy16(aSrc1, &As[0][g1]);
    async_copy16(bSrc1, &Bs[0][g1]);
    async_copy16(aSrc0 + 32, &As[1][g0]);
    async_copy16(bSrc0 + 32, &Bs[1][g0]);
    async_copy16(aSrc1 + 32, &As[1][g1]);
    async_copy16(bSrc1 + 32, &Bs[1][g1]);
    asm volatile("s_waitcnt vmcnt(4)" ::: "memory");
    __builtin_amdgcn_s_barrier();
    __builtin_amdgcn_sched_barrier(0);

    for (int t3 = 0; t3 < NT - 3; t3 += 3) {
        GEMM_BODY(0, 1, 2)
        GEMM_BODY(1, 1, 2)
        GEMM_BODY(2, 1, 2)
        aSrc0 += 96; aSrc1 += 96; bSrc0 += 96; bSrc1 += 96;
    }
    // tail macro-iter (t3 == NT-3): body0 prefetches tile NT-1
    GEMM_BODY(0, 1, 2)
    GEMM_BODY(1, 0, 1)
    GEMM_BODY(2, 0, 0)

    const int col_l = lane & 15, row_l = (lane >> 4) * 4;
#pragma unroll
    for (int i = 0; i < 4; ++i) {
#pragma unroll
        for (int j = 0; j < 4; ++j) {
            const int n = n0 + wc + j * 16 + col_l;
            const float bv = bias[n];
            const int mb = m0 + wr + i * 16 + row_l;
            if (EPI == 1) {
#pragma unroll
                for (int rg = 0; rg < 4; ++rg) {
                    float v = acc[i][j][rg] + bv;
                    v = 0.5f * v * (1.f + erff(v * 0.70710678118654752f));
                    ((unsigned short*)out)[(long)(mb + rg) * N + n] = f2bf(v);
                }
            } else if (EPI == 3) {
#pragma unroll
                for (int rg = 0; rg < 4; ++rg)
                    ((float*)out)[(long)(mb + rg) * N + n] =
                        acc[i][j][rg] + bv + resid[(long)(mb + rg) * N + n];
            } else {
                const int part = n / 768;          // 0=q, 1=k, 2=v
                const int nn = n - part * 768;
                const int hh = nn >> 6, dh = nn & 63;
                const int bb = mb >> 12, s0 = mb & 4095;  // const over rg
                if (part == 2) {
                    ushort4 ov;
#pragma unroll
                    for (int rg = 0; rg < 4; ++rg)
                        ((unsigned short*)&ov)[rg] = f2bf(acc[i][j][rg] + bv);
                    *(ushort4*)(out2 +
                        (((long)bb * NHEAD + hh) * DH + dh) * S_LEN + s0) = ov;
                } else {
#pragma unroll
                    for (int rg = 0; rg < 4; ++rg)
                        ((unsigned short*)out)[(long)part * NQC +
                            (((long)bb * NHEAD + hh) * S_LEN + s0 + rg) * DH + dh] =
                            f2bf(acc[i][j][rg] + bv);
                }
            }
        }
    }
}

// ---------------------------------------------------------------------------
// Split-K (x2) bf16 MFMA GEMM, same unrolled 3-buffer pipeline. Raw fp32
// partials; reduction happens inside ln2p_k. (Kept for Wo2: K=3072.)
// ---------------------------------------------------------------------------
__global__ __launch_bounds__(256) void gemm_sp(
    const unsigned short* __restrict__ A, const unsigned short* __restrict__ BT,
    float* __restrict__ p0, float* __restrict__ p1,
    int M, int N, int K2, int nx, int ntile)
{
    __shared__ unsigned short As[3][128 * 32];
    __shared__ unsigned short Bs[3][128 * 32];
    const int tid = threadIdx.x;
    const int wave = tid >> 6, lane = tid & 63;
    const int t8 = (blockIdx.x & 7) * (gridDim.x >> 3) + (blockIdx.x >> 3);
    const int slice = t8 >= ntile;
    const int tile = t8 - slice * ntile;
    const int m0 = (tile / nx) * 128, n0 = (tile % nx) * 128;
    const int kbeg = slice * K2;
    float* P = slice ? p1 : p0;
    const int wr = (wave >> 1) * 64, wc = (wave & 1) * 64;

    floatx4 acc[4][4];
#pragma unroll
    for (int i = 0; i < 4; ++i)
#pragma unroll
        for (int j = 0; j < 4; ++j) acc[i][j] = (floatx4){0.f, 0.f, 0.f, 0.f};

    const int srow = lane >> 2;
    const int schk = (((lane & 3) ^ (srow & 3))) * 8;
    const int r = lane & 15;
    const int q8 = ((lane >> 4) ^ (lane & 3)) * 8;
    const int rdA = (wr + r) * 32 + q8;
    const int rdB = (wc + r) * 32 + q8;
    const long Kl = (long)K2 * 2;

    const int NT = K2 >> 5;                             // NT % 3 == 0
    const unsigned short* aSrc0 = A  + (long)(m0 + wave * 32 + srow) * Kl + kbeg + schk;
    const unsigned short* aSrc1 = A  + (long)(m0 + wave * 32 + 16 + srow) * Kl + kbeg + schk;
    const unsigned short* bSrc0 = BT + (long)(n0 + wave * 32 + srow) * Kl + kbeg + schk;
    const unsigned short* bSrc1 = BT + (long)(n0 + wave * 32 + 16 + srow) * Kl + kbeg + schk;
    const int g0 = wave * 1024, g1 = wave * 1024 + 512;

    async_copy16(aSrc0, &As[0][g0]);
    async_copy16(bSrc0, &Bs[0][g0]);
    async_copy16(aSrc1, &As[0][g1]);
    async_copy16(bSrc1, &Bs[0][g1]);
    async_copy16(aSrc0 + 32, &As[1][g0]);
    async_copy16(bSrc0 + 32, &Bs[1][g0]);
    async_copy16(aSrc1 + 32, &As[1][g1]);
    async_copy16(bSrc1 + 32, &Bs[1][g1]);
    asm volatile("s_waitcnt vmcnt(4)" ::: "memory");
    __builtin_amdgcn_s_barrier();
    __builtin_amdgcn_sched_barrier(0);

    for (int t3 = 0; t3 < NT - 3; t3 += 3) {
        GEMM_BODY(0, 1, 2)
        GEMM_BODY(1, 1, 2)
        GEMM_BODY(2, 1, 2)
        aSrc0 += 96; aSrc1 += 96; bSrc0 += 96; bSrc1 += 96;
    }
    GEMM_BODY(0, 1, 2)
    GEMM_BODY(1, 0, 1)
    GEMM_BODY(2, 0, 0)

    const int col_l = lane & 15, row_l = (lane >> 4) * 4;
#pragma unroll
    for (int i = 0; i < 4; ++i)
#pragma unroll
        for (int j = 0; j < 4; ++j) {
            const int n = n0 + wc + j * 16 + col_l;
#pragma unroll
            for (int rg = 0; rg < 4; ++rg) {
                const int m = m0 + wr + i * 16 + row_l + rg;
                P[(long)m * N + n] = acc[i][j][rg];
            }
        }
}

// ---------------------------------------------------------------------------
// Fused attention: blocks [0,24) = global-query path (4 waves, 16 iters),
// blocks [24,792) = band path (b,h,chunk; 4 waves x 32 queries, KVBLK=64:
// 6 band 64-key tiles + 1 glob tile masked to kpos<NGLB; softmax passes
// and barriers halved vs KVBLK=32).
// Glob blocks launch FIRST so they overlap the band wave-front.
// Band suppresses stores for q0 < NGLB (those rows belong to glob) -> no race.
// ---------------------------------------------------------------------------
__global__ __launch_bounds__(256) void attn_k(
    const unsigned short* __restrict__ q, const unsigned short* __restrict__ k,
    const unsigned short* __restrict__ vt, const float* __restrict__ am,
    unsigned short* __restrict__ ctx)
{
    __shared__ __align__(16) unsigned char smem[36864];
    const int blk = blockIdx.x;
    const int tid = threadIdx.x;
    const int wave = tid >> 6, lane = tid & 63;
    const int ln15 = lane & 15, ln4 = lane >> 4;

    if (blk >= 24) {
        // ---------------- band path (KVBLK=64) ----------------
        unsigned short* Ks = (unsigned short*)smem;            // 64*72
        unsigned short* Vs = Ks + 64 * 72;                     // 64*72
        unsigned short* Ps = Vs + 64 * 72;                     // [4][32*72]

        const int bb = blk - 24;
        const int c = bb & 31;
        const int h = (bb >> 5) % NHEAD;
        const int b = bb / (32 * NHEAD);
        const long bh = (long)b * NHEAD + h;

        const unsigned short* kh  = k + bh * S_LEN * DH;
        const unsigned short* vth = vt + bh * (long)DH * S_LEN;
        const float* amb = am + (long)b * S_LEN;

        const int q0 = c * WINSZ + wave * 32;

        bf16x8 qf[2][2];
#pragma unroll
        for (int nt = 0; nt < 2; ++nt)
#pragma unroll
            for (int ks = 0; ks < 2; ++ks)
                qf[nt][ks] = *(const bf16x8*)(q + (bh * S_LEN + q0 + nt * 16 + ln15) * DH
                                              + ks * 32 + ln4 * 8);

        floatx4 o[4][2];
#pragma unroll
        for (int mt = 0; mt < 4; ++mt)
#pragma unroll
            for (int nt = 0; nt < 2; ++nt) o[mt][nt] = (floatx4){0.f, 0.f, 0.f, 0.f};
        float m_r[2] = {-1e30f, -1e30f}, l_r[2] = {0.f, 0.f};

        const int sk_key = tid >> 3, sk_ch = tid & 7;   // key 0..31(+32), ch 0..7
        const int sv_dim = tid & 63, sv_ch = tid >> 6;  // dim, col-grp 0..3(+32)
        const bf16x8 zero8 = {0, 0, 0, 0, 0, 0, 0, 0};

        for (int tile = 0; tile < 7; ++tile) {
            const bool glob = (tile == 6);
            const int kbase = glob ? 0 : (c * WINSZ - WINSZ + tile * 64);

            __syncthreads();
            {
                int kpos = kbase + sk_key;
                bf16x8 val = zero8;
                if ((unsigned)kpos < (unsigned)S_LEN)
                    val = *(const bf16x8*)(kh + (long)kpos * DH + sk_ch * 8);
                *(bf16x8*)(&Ks[sk_key * 72 + sk_ch * 8]) = val;
                kpos += 32;
                val = zero8;
                if ((unsigned)kpos < (unsigned)S_LEN)
                    val = *(const bf16x8*)(kh + (long)kpos * DH + sk_ch * 8);
                *(bf16x8*)(&Ks[(sk_key + 32) * 72 + sk_ch * 8]) = val;
            }
            {
                int kc = kbase + sv_ch * 8;
                bf16x8 val = zero8;
                if (kc >= 0 && kc + 8 <= S_LEN)
                    val = *(const bf16x8*)(vth + (long)sv_dim * S_LEN + kc);
                *(bf16x8*)(&Vs[sv_dim * 72 + sv_ch * 8]) = val;
                kc += 32;
                val = zero8;
                if (kc >= 0 && kc + 8 <= S_LEN)
                    val = *(const bf16x8*)(vth + (long)sv_dim * S_LEN + kc);
                *(bf16x8*)(&Vs[sv_dim * 72 + 32 + sv_ch * 8]) = val;
            }
            __syncthreads();

            bf16x8 ak[4][2];
#pragma unroll
            for (int mt = 0; mt < 4; ++mt)
#pragma unroll
                for (int ks = 0; ks < 2; ++ks)
                    ak[mt][ks] = *(const bf16x8*)(&Ks[(mt * 16 + ln15) * 72 + ks * 32 + ln4 * 8]);

            floatx4 s[4][2];
#pragma unroll
            for (int mt = 0; mt < 4; ++mt)
#pragma unroll
                for (int nt = 0; nt < 2; ++nt) {
                    floatx4 acc = (floatx4){0.f, 0.f, 0.f, 0.f};
                    acc = __builtin_amdgcn_mfma_f32_16x16x32_bf16(ak[mt][0], qf[nt][0], acc, 0, 0, 0);
                    acc = __builtin_amdgcn_mfma_f32_16x16x32_bf16(ak[mt][1], qf[nt][1], acc, 0, 0, 0);
                    s[mt][nt] = acc;
                }

#pragma unroll
            for (int mt = 0; mt < 4; ++mt) {
                const int kp0 = kbase + mt * 16 + ln4 * 4;
#pragma unroll
                for (int rg = 0; rg < 4; ++rg) {
                    const int kpos = kp0 + rg;
                    const bool kin = (unsigned)kpos < (unsigned)S_LEN;
                    const float amv = kin ? amb[kpos] : 0.f;
#pragma unroll
                    for (int nt = 0; nt < 2; ++nt) {
                        const int qpos = q0 + nt * 16 + ln15;
                        const int dlt = kpos > qpos ? kpos - qpos : qpos - kpos;
                        const bool valid = glob ? (kpos < NGLB)
                                                : (kpos >= NGLB && kin && dlt <= WINSZ);
                        s[mt][nt][rg] = valid ? s[mt][nt][rg] + amv : NEGV;
                    }
                }
            }

            float alpha[2];
#pragma unroll
            for (int nt = 0; nt < 2; ++nt) {
                float mx = s[0][nt][0];
#pragma unroll
                for (int mt = 0; mt < 4; ++mt)
#pragma unroll
                    for (int rg = 0; rg < 4; ++rg) mx = fmaxf(mx, s[mt][nt][rg]);
                mx = fmaxf(mx, __shfl_xor(mx, 16));
                mx = fmaxf(mx, __shfl_xor(mx, 32));
                const float mn = fmaxf(m_r[nt], mx);
                alpha[nt] = __expf(m_r[nt] - mn);
                m_r[nt] = mn;
            }

#pragma unroll
            for (int nt = 0; nt < 2; ++nt) {
                float sum = 0.f;
#pragma unroll
                for (int mt = 0; mt < 4; ++mt) {
                    ushort4 pk;
#pragma unroll
                    for (int rg = 0; rg < 4; ++rg) {
                        const float p = __expf(s[mt][nt][rg] - m_r[nt]);
                        sum += p;
                        ((unsigned short*)&pk)[rg] = f2bf(p);
                    }
                    *(ushort4*)(&Ps[wave * 2304 + (nt * 16 + ln15) * 72 + mt * 16 + ln4 * 4]) = pk;
                }
                sum += __shfl_xor(sum, 16);
                sum += __shfl_xor(sum, 32);
                l_r[nt] = l_r[nt] * alpha[nt] + sum;
            }

#pragma unroll
            for (int mt = 0; mt < 4; ++mt)
#pragma unroll
                for (int nt = 0; nt < 2; ++nt)
#pragma unroll
                    for (int rg = 0; rg < 4; ++rg) o[mt][nt][rg] *= alpha[nt];

            bf16x8 av[4][2], bp[2][2];
#pragma unroll
            for (int mt = 0; mt < 4; ++mt)
#pragma unroll
                for (int ks = 0; ks < 2; ++ks)
                    av[mt][ks] = *(const bf16x8*)(&Vs[(mt * 16 + ln15) * 72 + ks * 32 + ln4 * 8]);
#pragma unroll
            for (int nt = 0; nt < 2; ++nt)
#pragma unroll
                for (int ks = 0; ks < 2; ++ks)
                    bp[nt][ks] = *(const bf16x8*)(&Ps[wave * 2304 + (nt * 16 + ln15) * 72
                                                  + ks * 32 + ln4 * 8]);
#pragma unroll
            for (int mt = 0; mt < 4; ++mt)
#pragma unroll
                for (int nt = 0; nt < 2; ++nt) {
                    o[mt][nt] = __builtin_amdgcn_mfma_f32_16x16x32_bf16(
                        av[mt][0], bp[nt][0], o[mt][nt], 0, 0, 0);
                    o[mt][nt] = __builtin_amdgcn_mfma_f32_16x16x32_bf16(
                        av[mt][1], bp[nt][1], o[mt][nt], 0, 0, 0);
                }
        }

        if (q0 >= NGLB) {
            const float inv0 = 1.f / l_r[0], inv1 = 1.f / l_r[1];
#pragma unroll
            for (int nt = 0; nt < 2; ++nt) {
                const float inv = nt ? inv1 : inv0;
                const long row = (long)b * S_LEN + q0 + nt * 16 + ln15;
#pragma unroll
                for (int mt = 0; mt < 4; ++mt) {
                    ushort4 ov;
#pragma unroll
                    for (int rg = 0; rg < 4; ++rg)
                        ((unsigned short*)&ov)[rg] = f2bf(o[mt][nt][rg] * inv);
                    *(ushort4*)(ctx + row * D_MODEL + h * DH + mt * 16 + ln4 * 4) = ov;
                }
            }
        }
    } else {
        // ---------------- global-query path (4 waves, 16 iters) ----------------
        unsigned short* Psg = (unsigned short*)smem;           // [4][32*72]
        float* Om   = (float*)(smem + 18432);                  // 64*36
        float* mW   = (float*)(smem + 27648);                  // [4][32]
        float* lW   = (float*)(smem + 28160);                  // [4][32]
        float* lTot = (float*)(smem + 28672);                  // [32]

        const int bh = blk;
        const int b = bh / NHEAD, h = bh % NHEAD;

        const unsigned short* kh  = k + (long)bh * S_LEN * DH;
        const unsigned short* vth = vt + (long)bh * DH * S_LEN;
        const float* amb = am + (long)b * S_LEN;

        bf16x8 qf[2][2];
#pragma unroll
        for (int nt = 0; nt < 2; ++nt)
#pragma unroll
            for (int ks = 0; ks < 2; ++ks)
                qf[nt][ks] = *(const bf16x8*)(q + ((long)bh * S_LEN + nt * 16 + ln15) * DH
                                              + ks * 32 + ln4 * 8);

        floatx4 o[4][2];
#pragma unroll
        for (int mt = 0; mt < 4; ++mt)
#pragma unroll
            for (int nt = 0; nt < 2; ++nt) o[mt][nt] = (floatx4){0.f, 0.f, 0.f, 0.f};
        float m_r[2] = {-1e30f, -1e30f}, l_r[2] = {0.f, 0.f};

        for (int it = 0; it < 16; ++it) {
            const int kbase = it * 256 + wave * 64;

            bf16x8 ak[4][2];
#pragma unroll
            for (int mt = 0; mt < 4; ++mt)
#pragma unroll
                for (int ks = 0; ks < 2; ++ks)
                    ak[mt][ks] = *(const bf16x8*)(kh + (long)(kbase + mt * 16 + ln15) * DH
                                                  + ks * 32 + ln4 * 8);

            floatx4 s[4][2];
#pragma unroll
            for (int mt = 0; mt < 4; ++mt)
#pragma unroll
                for (int nt = 0; nt < 2; ++nt) {
                    floatx4 acc = (floatx4){0.f, 0.f, 0.f, 0.f};
                    acc = __builtin_amdgcn_mfma_f32_16x16x32_bf16(ak[mt][0], qf[nt][0], acc, 0, 0, 0);
                    acc = __builtin_amdgcn_mfma_f32_16x16x32_bf16(ak[mt][1], qf[nt][1], acc, 0, 0, 0);
                    s[mt][nt] = acc;
                }

#pragma unroll
            for (int mt = 0; mt < 4; ++mt) {
                const int kp0 = kbase + mt * 16 + ln4 * 4;
#pragma unroll
                for (int rg = 0; rg < 4; ++rg) {
                    const float amv = amb[kp0 + rg];
#pragma unroll
                    for (int nt = 0; nt < 2; ++nt) s[mt][nt][rg] += amv;
                }
            }

            float alpha[2];
#pragma unroll
            for (int nt = 0; nt < 2; ++nt) {
                float mx = s[0][nt][0];
#pragma unroll
                for (int mt = 0; mt < 4; ++mt)
#pragma unroll
                    for (int rg = 0; rg < 4; ++rg) mx = fmaxf(mx, s[mt][nt][rg]);
                mx = fmaxf(mx, __shfl_xor(mx, 16));
                mx = fmaxf(mx, __shfl_xor(mx, 32));
                const float mn = fmaxf(m_r[nt], mx);
                alpha[nt] = __expf(m_r[nt] - mn);
                m_r[nt] = mn;
            }

#pragma unroll
            for (int nt = 0; nt < 2; ++nt) {
                float sum = 0.f;
#pragma unroll
                for (int mt = 0; mt < 4; ++mt) {
                    ushort4 pk;
#pragma unroll
                    for (int rg = 0; rg < 4; ++rg) {
                        const float p = __expf(s[mt][nt][rg] - m_r[nt]);
                        sum += p;
                        ((unsigned short*)&pk)[rg] = f2bf(p);
                    }
                    *(ushort4*)(&Psg[wave * 2304 + (nt * 16 + ln15) * 72 + mt * 16 + ln4 * 4]) = pk;
                }
                sum += __shfl_xor(sum, 16);
                sum += __shfl_xor(sum, 32);
                l_r[nt] = l_r[nt] * alpha[nt] + sum;
            }

#pragma unroll
            for (int mt = 0; mt < 4; ++mt)
#pragma unroll
                for (int nt = 0; nt < 2; ++nt)
#pragma unroll
                    for (int rg = 0; rg < 4; ++rg) o[mt][nt][rg] *= alpha[nt];

            bf16x8 av[4][2], bp[2][2];
#pragma unroll
            for (int mt = 0; mt < 4; ++mt)
#pragma unroll
                for (int ks = 0; ks < 2; ++ks)
                    av[mt][ks] = *(const bf16x8*)(vth + (long)(mt * 16 + ln15) * S_LEN
                                                  + kbase + ks * 32 + ln4 * 8);
#pragma unroll
            for (int nt = 0; nt < 2; ++nt)
#pragma unroll
                for (int ks = 0; ks < 2; ++ks)
                    bp[nt][ks] = *(const bf16x8*)(&Psg[wave * 2304 + (nt * 16 + ln15) * 72
                                                  + ks * 32 + ln4 * 8]);
#pragma unroll
            for (int mt = 0; mt < 4; ++mt)
#pragma unroll
                for (int nt = 0; nt < 2; ++nt) {
                    o[mt][nt] = __builtin_amdgcn_mfma_f32_16x16x32_bf16(
                        av[mt][0], bp[nt][0], o[mt][nt], 0, 0, 0);
                    o[mt][nt] = __builtin_amdgcn_mfma_f32_16x16x32_bf16(
                        av[mt][1], bp[nt][1], o[mt][nt], 0, 0, 0);
                }
        }

        if (ln4 == 0) {
#pragma unroll
            for (int nt = 0; nt < 2; ++nt) {
                mW[wave * 32 + nt * 16 + ln15] = m_r[nt];
                lW[wave * 32 + nt * 16 + ln15] = l_r[nt];
            }
        }
        for (int i = tid; i < 64 * 36; i += 256) Om[i] = 0.f;
        __syncthreads();

        float f[2];
#pragma unroll
        for (int nt = 0; nt < 2; ++nt) {
            const int qq = nt * 16 + ln15;
            float mt_ = mW[qq];
#pragma unroll
            for (int w = 1; w < 4; ++w) mt_ = fmaxf(mt_, mW[w * 32 + qq]);
            float lt = 0.f;
#pragma unroll
            for (int w = 0; w < 4; ++w) lt += __expf(mW[w * 32 + qq] - mt_) * lW[w * 32 + qq];
            f[nt] = __expf(m_r[nt] - mt_);
            if (wave == 0 && ln4 == 0) lTot[qq] = lt;
        }
#pragma unroll
        for (int mt = 0; mt < 4; ++mt)
#pragma unroll
            for (int nt = 0; nt < 2; ++nt)
#pragma unroll
                for (int rg = 0; rg < 4; ++rg) o[mt][nt][rg] *= f[nt];

        for (int wv = 0; wv < 4; ++wv) {
            if (wave == wv) {
#pragma unroll
                for (int mt = 0; mt < 4; ++mt)
#pragma unroll
                    for (int nt = 0; nt < 2; ++nt)
#pragma unroll
                        for (int rg = 0; rg < 4; ++rg)
                            Om[(mt * 16 + ln4 * 4 + rg) * 36 + nt * 16 + ln15] += o[mt][nt][rg];
            }
            __syncthreads();
        }

        const int qq = tid >> 3, d0 = (tid & 7) * 8;
        const float inv = 1.f / lTot[qq];
        ushort4 ov0, ov1;
#pragma unroll
        for (int i = 0; i < 4; ++i)
            ((unsigned short*)&ov0)[i] = f2bf(Om[(d0 + i) * 36 + qq] * inv);
#pragma unroll
        for (int i = 0; i < 4; ++i)
            ((unsigned short*)&ov1)[i] = f2bf(Om[(d0 + 4 + i) * 36 + qq] * inv);
        unsigned short* dst = ctx + ((long)b * S_LEN + qq) * D_MODEL + h * DH + d0;
        *(ushort4*)dst = ov0;
        *(ushort4*)(dst + 4) = ov1;
    }
}

// ---------------------------------------------------------------------------
// Fused reduce + LayerNorm. x = p0 [+ p1] [+ bias] [+ resid] (null-skippable).
// One block per row (768 cols). Shfl wave-reduce (2 syncs).
// ---------------------------------------------------------------------------
__global__ __launch_bounds__(256) void ln2p_k(
    const float* __restrict__ p0, const float* __restrict__ p1,
    const float* __restrict__ bias, const float* __restrict__ resid,
    float* __restrict__ out, unsigned short* __restrict__ out_bf,
    const float* __restrict__ gw, const float* __restrict__ bw)
{
    __shared__ float red[8];
    const long base = (long)blockIdx.x * D_MODEL;
    const int t = threadIdx.x;
    const int wv = t >> 6, lane = t & 63;
    float v0 = p0[base + t];
    float v1 = p0[base + t + 256];
    float v2 = p0[base + t + 512];
    if (p1) {
        v0 += p1[base + t]; v1 += p1[base + t + 256]; v2 += p1[base + t + 512];
    }
    if (bias) {
        v0 += bias[t]; v1 += bias[t + 256]; v2 += bias[t + 512];
    }
    if (resid) {
        v0 += resid[base + t]; v1 += resid[base + t + 256]; v2 += resid[base + t + 512];
    }

    float s = v0 + v1 + v2;
#pragma unroll
    for (int off = 32; off; off >>= 1) s += __shfl_xor(s, off);
    if (lane == 0) red[wv] = s;
    __syncthreads();
    const float mu = (red[0] + red[1] + red[2] + red[3]) * (1.f / 768.f);

    const float d0 = v0 - mu, d1 = v1 - mu, d2 = v2 - mu;
    float s2 = d0 * d0 + d1 * d1 + d2 * d2;
#pragma unroll
    for (int off = 32; off; off >>= 1) s2 += __shfl_xor(s2, off);
    if (lane == 0) red[4 + wv] = s2;
    __syncthreads();
    const float var = (red[4] + red[5] + red[6] + red[7]) * (1.f / 768.f);
    const float rs = rsqrtf(var + 1e-12f);

    const float y0 = d0 * rs * gw[t] + bw[t];
    const float y1 = d1 * rs * gw[t + 256] + bw[t + 256];
    const float y2 = d2 * rs * gw[t + 512] + bw[t + 512];
    if (out) {
        float* y = out + base;
        y[t] = y0; y[t + 256] = y1; y[t + 512] = y2;
    }
    if (out_bf) {
        unsigned short* yb = out_bf + base;
        yb[t] = f2bf(y0); yb[t + 256] = f2bf(y1); yb[t + 512] = f2bf(y2);
    }
}

// ---------------------------------------------------------------------------
extern "C" void kernel_launch(void* const* d_in, const int* in_sizes, int n_in,
                              void* d_out, int out_size, void* d_ws, size_t ws_size,
                              hipStream_t stream)
{
    const float* hid  = (const float*)d_in[0];
    const float* am   = (const float*)d_in[1];
    const float* Wq   = (const float*)d_in[2];
    const float* bq   = (const float*)d_in[3];
    const float* Wk   = (const float*)d_in[4];
    const float* bk   = (const float*)d_in[5];
    const float* Wv   = (const float*)d_in[6];
    const float* bv   = (const float*)d_in[7];
    const float* Wo   = (const float*)d_in[8];
    const float* bo   = (const float*)d_in[9];
    const float* ln1g = (const float*)d_in[10];
    const float* ln1b = (const float*)d_in[11];
    const float* Wi   = (const float*)d_in[12];
    const float* bi   = (const float*)d_in[13];
    const float* Wo2  = (const float*)d_in[14];
    const float* bo2  = (const float*)d_in[15];
    const float* ln2g = (const float*)d_in[16];
    const float* ln2b = (const float*)d_in[17];

    const long M  = (long)B_SZ * S_LEN;                 // 8192
    const long NQ = NQC;                                // 6291456

    unsigned short* W16 = (unsigned short*)d_ws;
    unsigned short* qb   = W16;             // bf16 (B,NH,S,DH) — q|k contiguous
    unsigned short* kb   = W16 + NQ;
    unsigned short* vb   = W16 + 2 * NQ;    // (unused: V written transposed)
    unsigned short* vtb  = W16 + 3 * NQ;    // bf16 (B,NH,DH,S) — direct from QKV
    unsigned short* ctxb = W16 + 4 * NQ;    // bf16 (B,S,768)
    unsigned short* hidb = W16 + 5 * NQ;    // bf16 hidden
    unsigned short* wqt  = W16 + 6 * NQ;    // [Wq|Wk|Wv]^T contiguous 2304x768
    unsigned short* wkt  = wqt + 589824;
    unsigned short* wvt  = wkt + 589824;
    unsigned short* wot  = wvt + 589824;
    unsigned short* wit  = wot + 589824;    // 2359296
    unsigned short* wo2t = wit + 2359296;   // 2359296 -> ends at u16 44826624
    float* tmp   = (float*)(W16 + 44826624);  // attn_out fp32 -> ends u16 57409536
    float* partB1 = (float*)(W16 + 57409536); // Wo2 split slice1 -> ends u16 69992448
    float* bcat  = (float*)(W16 + 69992448);  // 2304 fp32
    // aliases over dead regions:
    float* zA = (float*)W16;                      // Wo pre-LN fp32 (over qb,kb)
    unsigned short* interb = W16;                 // Wi out (over qb..vtb)
    unsigned short* attnb  = hidb;                // LN1 bf16 (over hidb)
    float* partB0 = (float*)(W16 + 4 * NQ);       // Wo2 slice0 (over ctxb,hidb)
    (void)vb; (void)ws_size; (void)in_sizes; (void)n_in; (void)out_size;

    // fused prep: 6 transposes (+0.125 fold into Wq) + bcat (+0.125 bq) + conv
    prep_k<<<dim3(13065), dim3(32, 8), 0, stream>>>(
        Wq, Wk, Wv, Wo, Wi, Wo2, wqt, wkt, wvt, wot, wit, wo2t,
        bq, bk, bv, bcat, hid, hidb);

    dim3 blk(256);

    // fused QKV: one GEMM, N = 2304; q/k scatter + V written TRANSPOSED (vtb)
    gemm_bf<2><<<dim3(1152), blk, 0, stream>>>(hidb, wqt, bcat, qb,
                                               M, 2304, 768, 18, nullptr, vtb);

    // fused band (KVBLK=64) + global attention (glob blocks first for overlap)
    attn_k<<<dim3(792), blk, 0, stream>>>(qb, kb, vtb, am, ctxb);

    // Wo: no split-K (K=768). Epilogue fuses +bo +hid -> fp32 zA; then LN1.
    gemm_bf<3><<<dim3(384), blk, 0, stream>>>(ctxb, wot, bo, zA,
                                              M, 768, 768, 6, hid, nullptr);
    ln2p_k<<<dim3(M), blk, 0, stream>>>(zA, nullptr, nullptr, nullptr,
                                        tmp, attnb, ln1g, ln1b);

    // inter = gelu(attn_out @ Wi + bi)
    gemm_bf<1><<<dim3(1536), blk, 0, stream>>>(attnb, wit, bi, interb,
                                               M, 3072, 768, 24, nullptr, nullptr);

    // Wo2 split-K x2 -> partB0/partB1 ; LN2 fuses reduce+bias+resid
    gemm_sp<<<dim3(768), blk, 0, stream>>>(interb, wo2t, partB0, partB1,
                                           M, 768, 1536, 6, 384);
    ln2p_k<<<dim3(M), blk, 0, stream>>>(partB0, partB1, bo2, tmp,
                                        (float*)d_out, nullptr, ln2g, ln2b);
}